// Round 2
// baseline (820.760 us; speedup 1.0000x reference)
//
#include <hip/hip_runtime.h>
#include <hip/hip_cooperative_groups.h>
#include <math.h>

namespace cg = cooperative_groups;

#define B 4
#define S 1024
#define D 256
#define H 6
#define HD 64
#define NE 3
#define HHD 384
#define ROWS (B*S)
#define MAXN 128
#define NBLK 1024

typedef __attribute__((ext_vector_type(8))) short bf8_t;
typedef __attribute__((ext_vector_type(4))) float f32x4;

__device__ __forceinline__ float leaky(float x){ return x > 0.f ? x : 0.2f*x; }

__device__ __forceinline__ unsigned short f2bf(float f){
    union { float f; unsigned int u; } v; v.f = f;
    unsigned int u = v.u;
    return (unsigned short)((u + 0x7FFFu + ((u >> 16) & 1u)) >> 16);
}
__device__ __forceinline__ float bf2f(unsigned short h){
    union { unsigned int u; float f; } v; v.u = ((unsigned int)h) << 16;
    return v.f;
}
__device__ __forceinline__ float blo(unsigned int u){
    union { unsigned int u; float f; } v; v.u = u << 16; return v.f;
}
__device__ __forceinline__ float bhi(unsigned int u){
    union { unsigned int u; float f; } v; v.u = u & 0xffff0000u; return v.f;
}
__device__ __forceinline__ float i2f(int t){
    union { int i; float f; } v; v.i = t; return v.f;
}
__device__ __forceinline__ int f2i(float f){
    union { float f; int i; } v; v.f = f; return v.i;
}

// ---------- params ----------
struct P {
    const float *feature, *adj;
    const float *main_W1, *dep_W1, *main_W2, *dep_W2, *blend_W, *router_W;
    const int *doc_p, *sect_p;
    const float *main_a1s, *main_a1d, *dep_a1s, *dep_a1d;
    const float *main_a2s, *main_a2d, *dep_a2s, *dep_a2d;
    const float *blend_b;
    unsigned short *featbf; short *nbr; int4 *nbc;
    unsigned short *w1nk, *w2nk, *bwt;
    float *es8, *ed8, *gatebuf;
    unsigned short *htn4, *h2n4, *h1c4;
    float *f2s4, *f2d4, *meanV1p, *meanV2, *sumBuf, *rmask;
    float *outp;
};

// ---------- block ranges for prep ----------
#define PB_CONV   1024
#define PB_NBR    1024
#define PB_W1     1536
#define PB_W2     1536
#define PB_BW      256
#define PB_ZERO    177
#define PB_ROUTER 1024
#define PB_TOTAL  (PB_CONV + PB_NBR + PB_W1 + PB_W2 + PB_BW + PB_ZERO + PB_ROUTER)
#define NZERO     45088

// ---------- stage 0: prep (no block barriers; early returns OK) ----------
__device__ __forceinline__ void prep_task(const P& pp, int task, int tid)
{
    int blk = task;
    if (blk < PB_CONV){
        int idx = blk*256 + tid;                       // < ROWS*D/4
        float4 v = ((const float4*)pp.feature)[idx];
        ushort4 o;
        o.x = f2bf(v.x); o.y = f2bf(v.y); o.z = f2bf(v.z); o.w = f2bf(v.w);
        ((ushort4*)pp.featbf)[idx] = o;
        return;
    }
    blk -= PB_CONV;
    if (blk < PB_NBR){
        int wave = tid >> 6, lane = tid & 63;
        int row = blk*4 + wave;
        int b1 = S - *pp.sect_p - *pp.doc_p;
        int b2 = S - *pp.doc_p;
        const float* ar = pp.adj + (size_t)row*S + lane*16;
        float a[16];
        #pragma unroll
        for (int q = 0; q < 4; q++){
            float4 v = ((const float4*)ar)[q];
            a[q*4+0] = v.x; a[q*4+1] = v.y; a[q*4+2] = v.z; a[q*4+3] = v.w;
        }
        int t0 = lane*16;
        int k = 0, c1 = 0, c2 = 0;
        #pragma unroll
        for (int i = 0; i < 16; i++){
            if (a[i] > 0.f){
                k++;
                int t = t0 + i;
                if (t < b1) c1++;
                if (t < b2) c2++;
            }
        }
        int inc = k;
        #pragma unroll
        for (int d = 1; d < 64; d <<= 1){
            int u = __shfl_up(inc, d);
            if (lane >= d) inc += u;
        }
        int off = inc - k;
        int total = __shfl(inc, 63);
        int o = row*MAXN + off;
        #pragma unroll
        for (int i = 0; i < 16; i++){
            if (a[i] > 0.f) pp.nbr[o++] = (short)(t0 + i);
        }
        for (int d = 32; d; d >>= 1){
            c1 += __shfl_down(c1, d);
            c2 += __shfl_down(c2, d);
        }
        if (lane == 0) pp.nbc[row] = make_int4(total, c1, c2, 0);
        return;
    }
    blk -= PB_NBR;
    if (blk < PB_W1){
        int e = blk / 384;
        int idx = (blk - e*384)*256 + tid;             // < HHD*D
        const float* src = (e == 0) ? pp.main_W1 : pp.dep_W1 + (size_t)(e-1)*H*D*HD;
        int n = idx >> 8, k = idx & 255;
        int h = n >> 6, o = n & 63;
        pp.w1nk[(size_t)e*HHD*D + idx] = f2bf(src[(h*D + k)*HD + o]);
        return;
    }
    blk -= PB_W1;
    if (blk < PB_W2){
        int g = blk*256 + tid;                         // < 4*D*HHD
        int e = g / (D*HHD);
        int rem = g - e*(D*HHD);
        int n = rem / HHD, k = rem - n*HHD;
        const float* src = (e == 0) ? pp.main_W2 : pp.dep_W2 + (size_t)(e-1)*HHD*D;
        pp.w2nk[g] = f2bf(src[k*D + n]);
        return;
    }
    blk -= PB_W2;
    if (blk < PB_BW){
        int col = blk, k = tid;
        pp.bwt[col*D + k] = f2bf(pp.blend_W[k*D + col]);
        return;
    }
    blk -= PB_BW;
    if (blk < PB_ZERO){
        int idx = blk*256 + tid;
        if (idx < NZERO) pp.f2s4[idx] = 0.f;           // contiguous zero region base
        return;
    }
    blk -= PB_ZERO;
    {
        int wave = tid >> 6, lane = tid & 63;
        int row = blk*4 + wave;
        float4 xv = ((const float4*)(pp.feature + (size_t)row*D))[lane];
        int f = lane*4;
        float xa[4] = {xv.x, xv.y, xv.z, xv.w};
        float p0 = 0.f, p1 = 0.f, p2 = 0.f;
        #pragma unroll
        for (int j = 0; j < 4; j++){
            p0 += xa[j]*pp.router_W[(f+j)*NE + 0];
            p1 += xa[j]*pp.router_W[(f+j)*NE + 1];
            p2 += xa[j]*pp.router_W[(f+j)*NE + 2];
        }
        for (int off = 32; off; off >>= 1){
            p0 += __shfl_down(p0, off);
            p1 += __shfl_down(p1, off);
            p2 += __shfl_down(p2, off);
        }
        if (lane == 0){
            float p[3] = {p0, p1, p2};
            int ex = 0;
            for (int e = 1; e < NE; e++) if (p[e] <= p[ex]) ex = e;
            for (int e = 0; e < NE; e++) pp.rmask[e*ROWS + row] = (e == ex) ? 0.f : 1.f;
        }
    }
}

// ---------- stage 1: GEMM1 (x@W1) + fused es/ed + colmean + blend gate ----------
// tasks 0..767: expert slices (e = t/192, p = (t%192)/64, n0 = (t%64)*64)
// tasks 768..895: gate (mhalf = g/64, n0 = (g%64)*64)
__device__ __forceinline__ void g1_task(const P& pp, int task, int tid, float* smem)
{
    float (*ep)[2][64][17] = (float (*)[2][64][17])smem;
    int wave = tid >> 6, lane = tid & 63;
    int quad = lane >> 4, l16 = lane & 15;
    f32x4 z4 = {0.f,0.f,0.f,0.f};
    bf8_t bz = {0,0,0,0,0,0,0,0};

    if (task >= 768){
        // ---- blend gate GEMM ----
        int g = task - 768;
        int m0 = (g >> 6)*128;
        int n0 = (g & 63)*64;
        const unsigned short* arow0 = pp.bwt + (size_t)(m0 + wave*16 + l16)*D + quad*8;
        const unsigned short* arow1 = arow0 + (size_t)64*D;
        const unsigned short* brow[4];
        #pragma unroll
        for (int j = 0; j < 4; j++)
            brow[j] = pp.featbf + (size_t)(n0 + j*16 + l16)*D + quad*8;
        f32x4 acc[8] = {z4, z4, z4, z4, z4, z4, z4, z4};
        bf8_t a0F = *(const bf8_t*)(arow0);
        bf8_t a1F = *(const bf8_t*)(arow1);
        bf8_t bF[4];
        #pragma unroll
        for (int j = 0; j < 4; j++) bF[j] = *(const bf8_t*)(brow[j]);
        #pragma unroll
        for (int it = 0; it < D/32; it++){
            bf8_t a0C = a0F, a1C = a1F;
            bf8_t bC[4] = {bF[0], bF[1], bF[2], bF[3]};
            if (it + 1 < D/32){
                int kn = (it + 1)*32;
                a0F = *(const bf8_t*)(arow0 + kn);
                a1F = *(const bf8_t*)(arow1 + kn);
                #pragma unroll
                for (int j = 0; j < 4; j++) bF[j] = *(const bf8_t*)(brow[j] + kn);
            }
            #pragma unroll
            for (int j = 0; j < 4; j++){
                acc[j]   = __builtin_amdgcn_mfma_f32_16x16x32_bf16(a0C, bC[j], acc[j],   0, 0, 0);
                acc[4+j] = __builtin_amdgcn_mfma_f32_16x16x32_bf16(a1C, bC[j], acc[4+j], 0, 0, 0);
            }
        }
        int mbase0 = m0 + wave*16 + quad*4;
        int mbase1 = mbase0 + 64;
        float bias0[4], bias1[4];
        #pragma unroll
        for (int r = 0; r < 4; r++){ bias0[r] = pp.blend_b[mbase0 + r]; bias1[r] = pp.blend_b[mbase1 + r]; }
        float lsum = 0.f;
        #pragma unroll
        for (int j = 0; j < 4; j++){
            int rown = n0 + j*16 + l16;
            f32x4 st0, st1;
            #pragma unroll
            for (int r = 0; r < 4; r++){
                float g0 = 1.f/(1.f + __expf(-(acc[j][r] + bias0[r])));
                float g1 = 1.f/(1.f + __expf(-(acc[4+j][r] + bias1[r])));
                lsum += g0 + g1;
                st0[r] = g0; st1[r] = g1;
            }
            *(f32x4*)(pp.gatebuf + (size_t)rown*D + mbase0) = st0;
            *(f32x4*)(pp.gatebuf + (size_t)rown*D + mbase1) = st1;
        }
        float* redp = smem;
        redp[tid] = lsum;
        __syncthreads();
        for (int sft = 128; sft; sft >>= 1){
            if (tid < sft) redp[tid] += redp[tid + sft];
            __syncthreads();
        }
        if (tid == 0) atomicAdd(pp.sumBuf, redp[0]);
    } else {
        // ---- expert slice ----
        int e = task / 192;
        int rem = task - e*192;
        int p = rem >> 6;
        int n0 = (rem & 63)*64;
        int m0 = p*128;
        const unsigned short* arow0 = pp.w1nk + (size_t)e*HHD*D + (size_t)(m0 + wave*16 + l16)*D + quad*8;
        const unsigned short* arow1 = arow0 + (size_t)64*D;
        const unsigned short* brow[4];
        bool zr[4];
        #pragma unroll
        for (int j = 0; j < 4; j++){
            int n = n0 + j*16 + l16;
            brow[j] = pp.featbf + (size_t)n*D + quad*8;
            zr[j] = (e > 0) ? (pp.rmask[(size_t)(e-1)*ROWS + n] == 0.f) : false;
        }
        f32x4 acc[8] = {z4, z4, z4, z4, z4, z4, z4, z4};
        bf8_t a0F = *(const bf8_t*)(arow0);
        bf8_t a1F = *(const bf8_t*)(arow1);
        bf8_t bF[4];
        #pragma unroll
        for (int j = 0; j < 4; j++) bF[j] = zr[j] ? bz : *(const bf8_t*)(brow[j]);
        #pragma unroll
        for (int it = 0; it < D/32; it++){
            bf8_t a0C = a0F, a1C = a1F;
            bf8_t bC[4] = {bF[0], bF[1], bF[2], bF[3]};
            if (it + 1 < D/32){
                int kn = (it + 1)*32;
                a0F = *(const bf8_t*)(arow0 + kn);
                a1F = *(const bf8_t*)(arow1 + kn);
                #pragma unroll
                for (int j = 0; j < 4; j++) bF[j] = zr[j] ? bz : *(const bf8_t*)(brow[j] + kn);
            }
            #pragma unroll
            for (int j = 0; j < 4; j++){
                acc[j]   = __builtin_amdgcn_mfma_f32_16x16x32_bf16(a0C, bC[j], acc[j],   0, 0, 0);
                acc[4+j] = __builtin_amdgcn_mfma_f32_16x16x32_bf16(a1C, bC[j], acc[4+j], 0, 0, 0);
            }
        }
        int b = n0 >> 10;
        int mbase0 = m0 + wave*16 + quad*4;
        int mbase1 = mbase0 + 64;
        int obase = wave*16 + quad*4;
        int h0 = p*2, h1 = p*2 + 1;
        #pragma unroll
        for (int j = 0; j < 4; j++){
            int row = n0 + j*16 + l16;
            ushort4 o0, o1;
            o0.x = f2bf(acc[j][0]);   o0.y = f2bf(acc[j][1]);
            o0.z = f2bf(acc[j][2]);   o0.w = f2bf(acc[j][3]);
            o1.x = f2bf(acc[4+j][0]); o1.y = f2bf(acc[4+j][1]);
            o1.z = f2bf(acc[4+j][2]); o1.w = f2bf(acc[4+j][3]);
            *(ushort4*)(pp.htn4 + ((size_t)e*ROWS + row)*HHD + mbase0) = o0;
            *(ushort4*)(pp.htn4 + ((size_t)e*ROWS + row)*HHD + mbase1) = o1;
        }
        const float* a1sp = (e == 0) ? pp.main_a1s : pp.dep_a1s + (size_t)(e-1)*H*HD;
        const float* a1dp = (e == 0) ? pp.main_a1d : pp.dep_a1d + (size_t)(e-1)*H*HD;
        float s0v[4], d0v[4], s1v[4], d1v[4];
        #pragma unroll
        for (int r = 0; r < 4; r++){
            s0v[r] = a1sp[mbase0 + r]; d0v[r] = a1dp[mbase0 + r];
            s1v[r] = a1sp[mbase1 + r]; d1v[r] = a1dp[mbase1 + r];
        }
        #pragma unroll
        for (int j = 0; j < 4; j++){
            float ps0 = 0.f, pd0 = 0.f, ps1 = 0.f, pd1 = 0.f;
            #pragma unroll
            for (int r = 0; r < 4; r++){
                ps0 += acc[j][r]*s0v[r];   pd0 += acc[j][r]*d0v[r];
                ps1 += acc[4+j][r]*s1v[r]; pd1 += acc[4+j][r]*d1v[r];
            }
            ep[0][0][j*16 + l16][wave*4 + quad] = ps0;
            ep[0][1][j*16 + l16][wave*4 + quad] = pd0;
            ep[1][0][j*16 + l16][wave*4 + quad] = ps1;
            ep[1][1][j*16 + l16][wave*4 + quad] = pd1;
        }
        float* mvb = pp.meanV1p + ((size_t)e*B + b)*512;
        #pragma unroll
        for (int r = 0; r < 4; r++){
            float cm0 = acc[0][r] + acc[1][r] + acc[2][r] + acc[3][r];
            float cm1 = acc[4][r] + acc[5][r] + acc[6][r] + acc[7][r];
            for (int off = 8; off; off >>= 1){
                cm0 += __shfl_down(cm0, off, 16);
                cm1 += __shfl_down(cm1, off, 16);
            }
            if (l16 == 0){
                atomicAdd(mvb + (obase + r)*8 + h0, cm0*(1.f/(float)S));
                atomicAdd(mvb + (obase + r)*8 + h1, cm1*(1.f/(float)S));
            }
        }
        __syncthreads();
        {
            int hh = tid >> 7, arr = (tid >> 6) & 1, sl = tid & 63;
            float sum = 0.f;
            #pragma unroll
            for (int i = 0; i < 16; i++) sum += ep[hh][arr][sl][i];
            int n = n0 + sl;
            float* dst = arr ? pp.ed8 : pp.es8;
            dst[(((size_t)e*B + (n >> 10))*S + (n & 1023))*8 + (p*2 + hh)] = sum;
        }
    }
    __syncthreads();   // protect smem reuse by next looped task
}

// ---------- stage 2: attn1 gather (4-way wave split per (e,b,s); zero-V skip for deputies) ----------
__device__ __forceinline__ void a1_task(const P& pp, int task, int tid, float* smem)
{
    float* wrec = smem;                 // [128][8]
    float* pacc = smem + 1024;          // [3][64][8]
    float* pden = smem + 2560;          // [2][8]
    int wave = tid >> 6, lane = tid & 63;
    int eb = task >> 10;
    int s = task & 1023;
    int e = eb >> 2, b = eb & 3;
    int row = b*S + s;
    int4 c = pp.nbc[row];
    int lo = 0, hi = c.x;
    if (e == 1) hi = c.y;
    else if (e == 2){ lo = c.y; hi = c.z; }
    else if (e == 3){ lo = c.z; }
    int nn = hi - lo;
    const short* nl = pp.nbr + (size_t)row*MAXN;
    if (wave < 2){
        const float* esp = pp.es8 + (((size_t)e*B + b)*S + s)*8;
        f32x4 es_lo = *(const f32x4*)esp;
        f32x4 es_hi = *(const f32x4*)(esp + 4);
        float esv[6] = {es_lo[0], es_lo[1], es_lo[2], es_lo[3], es_hi[0], es_hi[1]};
        const float* edb = pp.ed8 + ((size_t)e*B + b)*S*8;
        int i = wave*64 + lane;
        float w[6] = {0,0,0,0,0,0};
        if (i < nn){
            int t = nl[lo + i];
            const float* epn = edb + (size_t)t*8;
            f32x4 d0 = *(const f32x4*)epn;
            f32x4 d1 = *(const f32x4*)(epn + 4);
            float edv[6] = {d0[0], d0[1], d0[2], d0[3], d1[0], d1[1]};
            #pragma unroll
            for (int h = 0; h < 6; h++) w[h] = __expf(leaky(esv[h] + edv[h]));
            // deputy neighbors with rmask==0 have exactly-zero V rows: skip their gather
            float zf = 0.f;
            if (e > 0 && pp.rmask[(size_t)(e-1)*ROWS + (size_t)b*S + t] == 0.f) zf = 1.f;
            f32x4 r0 = {w[0], w[1], w[2], w[3]};
            f32x4 r1 = {w[4], w[5], i2f(t), zf};
            *(f32x4*)&wrec[i*8]     = r0;
            *(f32x4*)&wrec[i*8 + 4] = r1;
        }
        #pragma unroll
        for (int h = 0; h < 6; h++){
            float x = w[h];
            for (int o2 = 32; o2; o2 >>= 1) x += __shfl_down(x, o2);
            if (lane == 0) pden[wave*8 + h] = x;
        }
    }
    __syncthreads();
    const unsigned short* Vb = pp.htn4 + ((size_t)e*ROWS + b*S)*HHD + lane;
    float acc[6] = {0,0,0,0,0,0};
    #pragma unroll 2
    for (int j = wave; j < nn; j += 4){
        f32x4 r0 = *(const f32x4*)&wrec[j*8];
        f32x4 r1 = *(const f32x4*)&wrec[j*8 + 4];
        if (r1[3] != 0.f) continue;            // V row exactly zero
        int t = f2i(r1[2]);
        const unsigned short* vp = Vb + (size_t)t*HHD;
        float v0 = bf2f(vp[0]);
        float v1 = bf2f(vp[64]);
        float v2 = bf2f(vp[128]);
        float v3 = bf2f(vp[192]);
        float v4 = bf2f(vp[256]);
        float v5 = bf2f(vp[320]);
        acc[0] += r0[0]*v0; acc[1] += r0[1]*v1;
        acc[2] += r0[2]*v2; acc[3] += r0[3]*v3;
        acc[4] += r1[0]*v4; acc[5] += r1[1]*v5;
    }
    if (wave >= 1){
        float* pb = pacc + (size_t)(wave-1)*512 + lane*8;
        f32x4 p0 = {acc[0], acc[1], acc[2], acc[3]};
        f32x4 p1 = {acc[4], acc[5], 0.f, 0.f};
        *(f32x4*)pb = p0;
        *(f32x4*)(pb + 4) = p1;
    }
    __syncthreads();
    if (wave == 0){
        unsigned short* outp = pp.h1c4 + ((size_t)e*ROWS + row)*HHD;
        const float* mv = pp.meanV1p + ((size_t)e*B + b)*512 + lane*8;
        #pragma unroll
        for (int h = 0; h < 6; h++){
            float den = pden[h] + pden[8 + h];
            float v = (nn > 0) ? (acc[h] + pacc[lane*8 + h] + pacc[512 + lane*8 + h] + pacc[1024 + lane*8 + h])/den
                               : mv[h];
            v = v > 0.f ? v : __expf(v) - 1.f;   // ELU
            outp[h*64 + lane] = f2bf(v);
        }
    }
    __syncthreads();
}

// ---------- stage 3: GEMM2 (h1@W2) + fused f2s/f2d + colmean ----------
// tasks 0..511: e = t/128, mhalf = (t%128)/64, n0 = (t%64)*64
__device__ __forceinline__ void g2_task(const P& pp, int task, int tid, float* smem)
{
    float (*ep)[2][64][17] = (float (*)[2][64][17])smem;
    int wave = tid >> 6, lane = tid & 63;
    int quad = lane >> 4, l16 = lane & 15;
    int e = task >> 7;
    int rem = task & 127;
    int m0 = (rem >> 6)*128;
    int n0 = (rem & 63)*64;
    f32x4 z4 = {0.f,0.f,0.f,0.f};
    const unsigned short* arow0 = pp.w2nk + (size_t)e*D*HHD + (size_t)(m0 + wave*16 + l16)*HHD + quad*8;
    const unsigned short* arow1 = arow0 + (size_t)64*HHD;
    const unsigned short* brow[4];
    #pragma unroll
    for (int j = 0; j < 4; j++)
        brow[j] = pp.h1c4 + (size_t)e*ROWS*HHD + (size_t)(n0 + j*16 + l16)*HHD + quad*8;
    f32x4 acc[8] = {z4, z4, z4, z4, z4, z4, z4, z4};
    bf8_t a0F = *(const bf8_t*)(arow0);
    bf8_t a1F = *(const bf8_t*)(arow1);
    bf8_t bF[4];
    #pragma unroll
    for (int j = 0; j < 4; j++) bF[j] = *(const bf8_t*)(brow[j]);
    #pragma unroll
    for (int it = 0; it < HHD/32; it++){
        bf8_t a0C = a0F, a1C = a1F;
        bf8_t bC[4] = {bF[0], bF[1], bF[2], bF[3]};
        if (it + 1 < HHD/32){
            int kn = (it + 1)*32;
            a0F = *(const bf8_t*)(arow0 + kn);
            a1F = *(const bf8_t*)(arow1 + kn);
            #pragma unroll
            for (int j = 0; j < 4; j++) bF[j] = *(const bf8_t*)(brow[j] + kn);
        }
        #pragma unroll
        for (int j = 0; j < 4; j++){
            acc[j]   = __builtin_amdgcn_mfma_f32_16x16x32_bf16(a0C, bC[j], acc[j],   0, 0, 0);
            acc[4+j] = __builtin_amdgcn_mfma_f32_16x16x32_bf16(a1C, bC[j], acc[4+j], 0, 0, 0);
        }
    }
    int b = n0 >> 10;
    int mbase0 = m0 + wave*16 + quad*4;
    int mbase1 = mbase0 + 64;
    #pragma unroll
    for (int j = 0; j < 4; j++){
        int row = n0 + j*16 + l16;
        ushort4 o0, o1;
        o0.x = f2bf(acc[j][0]);   o0.y = f2bf(acc[j][1]);
        o0.z = f2bf(acc[j][2]);   o0.w = f2bf(acc[j][3]);
        o1.x = f2bf(acc[4+j][0]); o1.y = f2bf(acc[4+j][1]);
        o1.z = f2bf(acc[4+j][2]); o1.w = f2bf(acc[4+j][3]);
        *(ushort4*)(pp.h2n4 + ((size_t)e*ROWS + row)*D + mbase0) = o0;
        *(ushort4*)(pp.h2n4 + ((size_t)e*ROWS + row)*D + mbase1) = o1;
    }
    const float* a2sp = (e == 0) ? pp.main_a2s : pp.dep_a2s + (size_t)(e-1)*D;
    const float* a2dp = (e == 0) ? pp.main_a2d : pp.dep_a2d + (size_t)(e-1)*D;
    float s0v[4], d0v[4], s1v[4], d1v[4];
    #pragma unroll
    for (int r = 0; r < 4; r++){
        s0v[r] = a2sp[mbase0 + r]; d0v[r] = a2dp[mbase0 + r];
        s1v[r] = a2sp[mbase1 + r]; d1v[r] = a2dp[mbase1 + r];
    }
    #pragma unroll
    for (int j = 0; j < 4; j++){
        float ps0 = 0.f, pd0 = 0.f, ps1 = 0.f, pd1 = 0.f;
        #pragma unroll
        for (int r = 0; r < 4; r++){
            ps0 += acc[j][r]*s0v[r];   pd0 += acc[j][r]*d0v[r];
            ps1 += acc[4+j][r]*s1v[r]; pd1 += acc[4+j][r]*d1v[r];
        }
        ep[0][0][j*16 + l16][wave*4 + quad] = ps0;
        ep[0][1][j*16 + l16][wave*4 + quad] = pd0;
        ep[1][0][j*16 + l16][wave*4 + quad] = ps1;
        ep[1][1][j*16 + l16][wave*4 + quad] = pd1;
    }
    #pragma unroll
    for (int r = 0; r < 4; r++){
        float cm0 = acc[0][r] + acc[1][r] + acc[2][r] + acc[3][r];
        float cm1 = acc[4][r] + acc[5][r] + acc[6][r] + acc[7][r];
        for (int off = 8; off; off >>= 1){
            cm0 += __shfl_down(cm0, off, 16);
            cm1 += __shfl_down(cm1, off, 16);
        }
        if (l16 == 0){
            atomicAdd(pp.meanV2 + ((size_t)e*B + b)*D + mbase0 + r, cm0*(1.f/(float)S));
            atomicAdd(pp.meanV2 + ((size_t)e*B + b)*D + mbase1 + r, cm1*(1.f/(float)S));
        }
    }
    __syncthreads();
    {
        int hh = tid >> 7, arr = (tid >> 6) & 1, sl = tid & 63;
        float sum = 0.f;
        #pragma unroll
        for (int i = 0; i < 16; i++) sum += ep[hh][arr][sl][i];
        int n = n0 + sl;
        float* dst = arr ? pp.f2d4 : pp.f2s4;
        atomicAdd(dst + (size_t)e*ROWS + n, sum);
    }
    __syncthreads();   // protect smem reuse by next looped task
}

// ---------- stage 4: attn2 + blend ----------
// tasks 0..4095: b = t>>10, s = t&1023
__device__ __forceinline__ void a2_task(const P& pp, int task, int tid, float* smem)
{
    float2* wrec0 = (float2*)smem;            // [128]
    float2* wrec1 = (float2*)(smem + 256);    // [128]
    float*  pacc  = smem + 512;               // [3][256]
    float*  pden  = smem + 1280;              // [4][4]
    int wave = tid >> 6, lane = tid & 63;
    int b = task >> 10, s = task & 1023;
    int row = b*S + s;
    int4 c = pp.nbc[row];
    float rm0 = pp.rmask[row], rm1 = pp.rmask[ROWS + row], rm2 = pp.rmask[2*ROWS + row];
    const short* nl = pp.nbr + (size_t)row*MAXN;
    // ---- weight phase ----
    if (wave < 2){
        int i = wave*64 + lane;
        float w = 0.f;
        if (i < c.x){
            int t = nl[i];
            float fs = pp.f2s4[row];
            w = __expf(leaky(fs + pp.f2d4[(size_t)b*S + t]));
            float2 r; r.x = w; r.y = i2f(t);
            wrec0[i] = r;
        }
        float dsum = w;
        for (int o2 = 32; o2; o2 >>= 1) dsum += __shfl_down(dsum, o2);
        if (lane == 0) pden[wave*4 + 0] = dsum;
    } else {
        int i = (wave - 2)*64 + lane;
        float w = 0.f, d1 = 0.f, d2 = 0.f, d3 = 0.f;
        if (i < c.x){
            int t = nl[i];
            int tag = (i < c.y) ? 1 : ((i < c.z) ? 2 : 3);
            float act = (tag == 1) ? rm0 : ((tag == 2) ? rm1 : rm2);
            if (act != 0.f){
                float fs = pp.f2s4[(size_t)tag*ROWS + row];
                w = __expf(leaky(fs + pp.f2d4[(size_t)tag*ROWS + (size_t)b*S + t]));
            }
            float2 r; r.x = w; r.y = i2f(t);
            wrec1[i] = r;
            if (tag == 1) d1 = w; else if (tag == 2) d2 = w; else d3 = w;
        }
        for (int o2 = 32; o2; o2 >>= 1){
            d1 += __shfl_down(d1, o2);
            d2 += __shfl_down(d2, o2);
            d3 += __shfl_down(d3, o2);
        }
        if (lane == 0){ pden[wave*4 + 1] = d1; pden[wave*4 + 2] = d2; pden[wave*4 + 3] = d3; }
    }
    __syncthreads();
    // ---- gather phase ----
    float acc[4] = {0.f, 0.f, 0.f, 0.f};
    if (wave < 2){
        float inv = 1.f/(pden[0] + pden[4]);   // c.x >= 1 (self-loop) always
        const unsigned short* V = pp.h2n4 + (size_t)b*S*D;
        #pragma unroll 4
        for (int j = wave; j < c.x; j += 2){
            float2 r = wrec0[j];
            float wv = r.x*inv;
            int t = f2i(r.y);
            const unsigned short* vp = V + (size_t)t*D + lane*4;
            uint2 dv = *(const uint2*)vp;
            acc[0] += wv*blo(dv.x); acc[1] += wv*bhi(dv.x);
            acc[2] += wv*blo(dv.y); acc[3] += wv*bhi(dv.y);
        }
    } else {
        int rlo[3] = {0, c.y, c.z};
        int rhi[3] = {c.y, c.z, c.x};
        float ract[3] = {rm0, rm1, rm2};
        for (int rg = 0; rg < 3; rg++){
            if (ract[rg] == 0.f || rhi[rg] <= rlo[rg]) continue;
            float inv = 1.f/(pden[2*4 + rg + 1] + pden[3*4 + rg + 1]);
            const unsigned short* V = pp.h2n4 + ((size_t)(rg+1)*ROWS + (size_t)b*S)*D;
            #pragma unroll 4
            for (int j = rlo[rg] + (wave - 2); j < rhi[rg]; j += 2){
                float2 r = wrec1[j];
                float wv = r.x*inv;
                int t = f2i(r.y);
                const unsigned short* vp = V + (size_t)t*D + lane*4;
                uint2 dv = *(const uint2*)vp;
                acc[0] += wv*blo(dv.x); acc[1] += wv*bhi(dv.x);
                acc[2] += wv*blo(dv.y); acc[3] += wv*bhi(dv.y);
            }
        }
    }
    if (wave >= 1){
        #pragma unroll
        for (int q = 0; q < 4; q++) pacc[(size_t)(wave-1)*256 + lane*4 + q] = acc[q];
    }
    __syncthreads();
    // ---- combine + blend (wave 0) ----
    if (wave == 0){
        float4 g4 = *(const float4*)(pp.gatebuf + (size_t)row*D + lane*4);
        float dep_mv[4] = {0.f, 0.f, 0.f, 0.f};
        if (rm0 != 0.f && c.y == 0){
            float4 mv = *(const float4*)(pp.meanV2 + ((size_t)1*B + b)*D + lane*4);
            dep_mv[0] += mv.x; dep_mv[1] += mv.y; dep_mv[2] += mv.z; dep_mv[3] += mv.w;
        }
        if (rm1 != 0.f && c.z == c.y){
            float4 mv = *(const float4*)(pp.meanV2 + ((size_t)2*B + b)*D + lane*4);
            dep_mv[0] += mv.x; dep_mv[1] += mv.y; dep_mv[2] += mv.z; dep_mv[3] += mv.w;
        }
        if (rm2 != 0.f && c.x == c.z){
            float4 mv = *(const float4*)(pp.meanV2 + ((size_t)3*B + b)*D + lane*4);
            dep_mv[0] += mv.x; dep_mv[1] += mv.y; dep_mv[2] += mv.z; dep_mv[3] += mv.w;
        }
        float g[4] = {g4.x, g4.y, g4.z, g4.w};
        float4 o;
        float* op = &o.x;
        #pragma unroll
        for (int q = 0; q < 4; q++){
            int col = lane*4 + q;
            float a0 = acc[q] + pacc[col];
            float dep = pacc[256 + col] + pacc[512 + col] + dep_mv[q];
            op[q] = g[q]*a0 + (1.f - g[q])*dep;
        }
        *(float4*)(pp.outp + (size_t)row*D + lane*4) = o;
    }
    if (task == 0 && tid == 0){
        float mc = pp.sumBuf[0] / (float)(ROWS*D);
        pp.outp[ROWS*D]     = fabsf(mc - 0.6f)*0.01f;
        pp.outp[ROWS*D + 1] = mc;
    }
    __syncthreads();
}

// ---------- fused cooperative pipeline ----------
__global__ __launch_bounds__(256, 4) void fused_kernel(P pp)
{
    __shared__ __align__(16) float smem[4352];   // 17408 B (max over stages)
    cg::grid_group gg = cg::this_grid();
    int tid = threadIdx.x;
    for (int t = blockIdx.x; t < PB_TOTAL; t += NBLK) prep_task(pp, t, tid);
    gg.sync();
    for (int t = blockIdx.x; t < 896; t += NBLK) g1_task(pp, t, tid, smem);
    gg.sync();
    for (int t = blockIdx.x; t < 16384; t += NBLK) a1_task(pp, t, tid, smem);
    gg.sync();
    for (int t = blockIdx.x; t < 512; t += NBLK) g2_task(pp, t, tid, smem);
    gg.sync();
    for (int t = blockIdx.x; t < 4096; t += NBLK) a2_task(pp, t, tid, smem);
}

// ---------- standalone fallback wrappers (used if cooperative launch unsupported) ----------
__global__ __launch_bounds__(256) void prep_sk(P pp){ prep_task(pp, blockIdx.x, threadIdx.x); }
__global__ __launch_bounds__(256, 4) void g1_sk(P pp){
    __shared__ __align__(16) float smem[4352];
    g1_task(pp, blockIdx.x, threadIdx.x, smem);
}
__global__ __launch_bounds__(256) void a1_sk(P pp){
    __shared__ __align__(16) float smem[2576];
    a1_task(pp, blockIdx.x, threadIdx.x, smem);
}
__global__ __launch_bounds__(256, 4) void g2_sk(P pp){
    __shared__ __align__(16) float smem[4352];
    g2_task(pp, blockIdx.x, threadIdx.x, smem);
}
__global__ __launch_bounds__(256) void a2_sk(P pp){
    __shared__ __align__(16) float smem[1296];
    a2_task(pp, blockIdx.x, threadIdx.x, smem);
}

extern "C" void kernel_launch(void* const* d_in, const int* in_sizes, int n_in,
                              void* d_out, int out_size, void* d_ws, size_t ws_size,
                              hipStream_t stream)
{
    P hp;
    hp.feature  = (const float*)d_in[0];
    hp.adj      = (const float*)d_in[1];
    hp.main_W1  = (const float*)d_in[2];
    hp.main_a1s = (const float*)d_in[3];
    hp.main_a1d = (const float*)d_in[4];
    hp.main_W2  = (const float*)d_in[5];
    hp.main_a2s = (const float*)d_in[6];
    hp.main_a2d = (const float*)d_in[7];
    hp.dep_W1   = (const float*)d_in[8];
    hp.dep_a1s  = (const float*)d_in[9];
    hp.dep_a1d  = (const float*)d_in[10];
    hp.dep_W2   = (const float*)d_in[11];
    hp.dep_a2s  = (const float*)d_in[12];
    hp.dep_a2d  = (const float*)d_in[13];
    hp.router_W = (const float*)d_in[14];
    hp.blend_W  = (const float*)d_in[15];
    hp.blend_b  = (const float*)d_in[16];
    hp.doc_p    = (const int*)d_in[17];
    hp.sect_p   = (const int*)d_in[18];

    char* ws = (char*)d_ws;
    size_t off = 0;
    hp.featbf = (unsigned short*)(ws + off); off += (size_t)ROWS*D*2;        // 2 MB
    hp.nbr    = (short*)(ws + off);          off += (size_t)ROWS*MAXN*2;     // 1 MB
    hp.nbc    = (int4*)(ws + off);           off += (size_t)ROWS*16;         // 64 KB
    hp.w1nk   = (unsigned short*)(ws + off); off += (size_t)4*HHD*D*2;
    hp.w2nk   = (unsigned short*)(ws + off); off += (size_t)4*D*HHD*2;
    hp.bwt    = (unsigned short*)(ws + off); off += (size_t)D*D*2;
    hp.es8 = (float*)(ws + off); off += (size_t)4*B*S*8*4;   // 512 KB
    hp.ed8 = (float*)(ws + off); off += (size_t)4*B*S*8*4;   // 512 KB
    hp.gatebuf = (float*)(ws + off); off += (size_t)ROWS*D*4;                // 4 MB
    hp.htn4 = (unsigned short*)(ws + off); off += (size_t)4*ROWS*HHD*2;      // 12 MB
    hp.h2n4 = (unsigned short*)(ws + off); off += (size_t)4*ROWS*D*2;        // 8 MB
    hp.h1c4 = (unsigned short*)(ws + off); off += (size_t)4*ROWS*HHD*2;      // 12 MB
    // contiguous zero region (NZERO floats) starts at f2s4:
    hp.f2s4    = (float*)(ws + off); off += (size_t)4*ROWS*4;
    hp.f2d4    = (float*)(ws + off); off += (size_t)4*ROWS*4;
    hp.meanV1p = (float*)(ws + off); off += (size_t)4*B*512*4;
    hp.meanV2  = (float*)(ws + off); off += (size_t)4*B*D*4;
    hp.sumBuf  = (float*)(ws + off); off += 128;
    hp.rmask   = (float*)(ws + off); off += (size_t)NE*ROWS*4;
    hp.outp    = (float*)d_out;

    void* args[] = { (void*)&hp };
    hipError_t err = hipLaunchCooperativeKernel((void*)fused_kernel,
                                                dim3(NBLK), dim3(256),
                                                args, 0, stream);
    if (err != hipSuccess){
        // fallback: classic 5-launch pipeline with identical task code
        prep_sk<<<PB_TOTAL, 256, 0, stream>>>(hp);
        g1_sk<<<896,   256, 0, stream>>>(hp);
        a1_sk<<<16384, 256, 0, stream>>>(hp);
        g2_sk<<<512,   256, 0, stream>>>(hp);
        a2_sk<<<4096,  256, 0, stream>>>(hp);
    }
}

// Round 3
// 349.103 us; speedup vs baseline: 2.3511x; 2.3511x over previous
//
#include <hip/hip_runtime.h>
#include <math.h>

#define B 4
#define S 1024
#define D 256
#define H 6
#define HD 64
#define NE 3
#define HHD 384
#define ROWS (B*S)
#define MAXN 128
#define REP 2   // instrumentation: double each kernel's work so it rises above harness fills in rocprof

typedef __attribute__((ext_vector_type(8))) short bf8_t;
typedef __attribute__((ext_vector_type(4))) float f32x4;

__device__ __forceinline__ float leaky(float x){ return x > 0.f ? x : 0.2f*x; }

__device__ __forceinline__ unsigned short f2bf(float f){
    union { float f; unsigned int u; } v; v.f = f;
    unsigned int u = v.u;
    return (unsigned short)((u + 0x7FFFu + ((u >> 16) & 1u)) >> 16);
}
__device__ __forceinline__ float bf2f(unsigned short h){
    union { unsigned int u; float f; } v; v.u = ((unsigned int)h) << 16;
    return v.f;
}
__device__ __forceinline__ float blo(unsigned int u){
    union { unsigned int u; float f; } v; v.u = u << 16; return v.f;
}
__device__ __forceinline__ float bhi(unsigned int u){
    union { unsigned int u; float f; } v; v.u = u & 0xffff0000u; return v.f;
}
__device__ __forceinline__ float i2f(int t){
    union { int i; float f; } v; v.i = t; return v.f;
}
__device__ __forceinline__ int f2i(float f){
    union { float f; int i; } v; v.f = f; return v.i;
}

// ---------- params ----------
struct P {
    const float *feature, *adj;
    const float *main_W1, *dep_W1, *main_W2, *dep_W2, *blend_W, *router_W;
    const int *doc_p, *sect_p;
    const float *main_a1s, *main_a1d, *dep_a1s, *dep_a1d;
    const float *main_a2s, *main_a2d, *dep_a2s, *dep_a2d;
    const float *blend_b;
    unsigned short *featbf; short *nbr; int4 *nbc;
    unsigned short *w1nk, *w2nk, *bwt;
    float *es8, *ed8, *gatebuf;
    unsigned short *htn4, *h2n4, *h1c4;
    float *f2s4, *f2d4, *meanV1p, *meanV2, *sumBuf, *rmask;
    float *outp;
};

// ---------- block ranges for prep ----------
#define PB_CONV   1024
#define PB_NBR    1024
#define PB_W1     1536
#define PB_W2     1536
#define PB_BW      256
#define PB_ZERO    177
#define PB_ROUTER 1024
#define PB_TOTAL  (PB_CONV + PB_NBR + PB_W1 + PB_W2 + PB_BW + PB_ZERO + PB_ROUTER)
#define NZERO     45088

// ---------- prep task (idempotent; safe to repeat) ----------
__device__ __forceinline__ void prep_task(const P& pp, int task, int tid)
{
    int blk = task;
    if (blk < PB_CONV){
        int idx = blk*256 + tid;                       // < ROWS*D/4
        float4 v = ((const float4*)pp.feature)[idx];
        ushort4 o;
        o.x = f2bf(v.x); o.y = f2bf(v.y); o.z = f2bf(v.z); o.w = f2bf(v.w);
        ((ushort4*)pp.featbf)[idx] = o;
        return;
    }
    blk -= PB_CONV;
    if (blk < PB_NBR){
        int wave = tid >> 6, lane = tid & 63;
        int row = blk*4 + wave;
        int b1 = S - *pp.sect_p - *pp.doc_p;
        int b2 = S - *pp.doc_p;
        const float* ar = pp.adj + (size_t)row*S + lane*16;
        float a[16];
        #pragma unroll
        for (int q = 0; q < 4; q++){
            float4 v = ((const float4*)ar)[q];
            a[q*4+0] = v.x; a[q*4+1] = v.y; a[q*4+2] = v.z; a[q*4+3] = v.w;
        }
        int t0 = lane*16;
        int k = 0, c1 = 0, c2 = 0;
        #pragma unroll
        for (int i = 0; i < 16; i++){
            if (a[i] > 0.f){
                k++;
                int t = t0 + i;
                if (t < b1) c1++;
                if (t < b2) c2++;
            }
        }
        int inc = k;
        #pragma unroll
        for (int d = 1; d < 64; d <<= 1){
            int u = __shfl_up(inc, d);
            if (lane >= d) inc += u;
        }
        int off = inc - k;
        int total = __shfl(inc, 63);
        int o = row*MAXN + off;
        #pragma unroll
        for (int i = 0; i < 16; i++){
            if (a[i] > 0.f) pp.nbr[o++] = (short)(t0 + i);
        }
        for (int d = 32; d; d >>= 1){
            c1 += __shfl_down(c1, d);
            c2 += __shfl_down(c2, d);
        }
        if (lane == 0) pp.nbc[row] = make_int4(total, c1, c2, 0);
        return;
    }
    blk -= PB_NBR;
    if (blk < PB_W1){
        int e = blk / 384;
        int idx = (blk - e*384)*256 + tid;             // < HHD*D
        const float* src = (e == 0) ? pp.main_W1 : pp.dep_W1 + (size_t)(e-1)*H*D*HD;
        int n = idx >> 8, k = idx & 255;
        int h = n >> 6, o = n & 63;
        pp.w1nk[(size_t)e*HHD*D + idx] = f2bf(src[(h*D + k)*HD + o]);
        return;
    }
    blk -= PB_W1;
    if (blk < PB_W2){
        int g = blk*256 + tid;                         // < 4*D*HHD
        int e = g / (D*HHD);
        int rem = g - e*(D*HHD);
        int n = rem / HHD, k = rem - n*HHD;
        const float* src = (e == 0) ? pp.main_W2 : pp.dep_W2 + (size_t)(e-1)*HHD*D;
        pp.w2nk[g] = f2bf(src[k*D + n]);
        return;
    }
    blk -= PB_W2;
    if (blk < PB_BW){
        int col = blk, k = tid;
        pp.bwt[col*D + k] = f2bf(pp.blend_W[k*D + col]);
        return;
    }
    blk -= PB_BW;
    if (blk < PB_ZERO){
        int idx = blk*256 + tid;
        if (idx < NZERO) pp.f2s4[idx] = 0.f;           // contiguous zero region base
        return;
    }
    blk -= PB_ZERO;
    {
        int wave = tid >> 6, lane = tid & 63;
        int row = blk*4 + wave;
        float4 xv = ((const float4*)(pp.feature + (size_t)row*D))[lane];
        int f = lane*4;
        float xa[4] = {xv.x, xv.y, xv.z, xv.w};
        float p0 = 0.f, p1 = 0.f, p2 = 0.f;
        #pragma unroll
        for (int j = 0; j < 4; j++){
            p0 += xa[j]*pp.router_W[(f+j)*NE + 0];
            p1 += xa[j]*pp.router_W[(f+j)*NE + 1];
            p2 += xa[j]*pp.router_W[(f+j)*NE + 2];
        }
        for (int off = 32; off; off >>= 1){
            p0 += __shfl_down(p0, off);
            p1 += __shfl_down(p1, off);
            p2 += __shfl_down(p2, off);
        }
        if (lane == 0){
            float p[3] = {p0, p1, p2};
            int ex = 0;
            for (int e = 1; e < NE; e++) if (p[e] <= p[ex]) ex = e;
            for (int e = 0; e < NE; e++) pp.rmask[e*ROWS + row] = (e == ex) ? 0.f : 1.f;
        }
    }
}

__global__ __launch_bounds__(256) void prep_kernel(P pp)
{
    #pragma unroll 1
    for (int rep = 0; rep < REP; rep++){
        prep_task(pp, blockIdx.x, threadIdx.x);
        __syncthreads();
    }
}

// ---------- GEMM1 (x@W1) + fused es/ed + colmean; htn4 stored head-pair-packed ----------
// grid (3, ROWS/64, 5). z<4: expert slices; z==4: blend gate (x<2).
__global__ __launch_bounds__(256, 4) void gemm1_kernel(P pp)
{
    __shared__ float ep[2][2][64][17];      // 17408 B
    int tid = threadIdx.x, wave = tid >> 6, lane = tid & 63;
    int quad = lane >> 4, l16 = lane & 15;
    int e = blockIdx.z;
    int n0 = blockIdx.y*64;
    f32x4 z4 = {0.f,0.f,0.f,0.f};
    bf8_t bz = {0,0,0,0,0,0,0,0};
    if (e == 4 && blockIdx.x >= 2) return;

    #pragma unroll 1
    for (int rep = 0; rep < REP; rep++){
    if (e == 4){
        // ---- blend gate GEMM ----
        int m0 = blockIdx.x*128;
        const unsigned short* arow0 = pp.bwt + (size_t)(m0 + wave*16 + l16)*D + quad*8;
        const unsigned short* arow1 = arow0 + (size_t)64*D;
        const unsigned short* brow[4];
        #pragma unroll
        for (int j = 0; j < 4; j++)
            brow[j] = pp.featbf + (size_t)(n0 + j*16 + l16)*D + quad*8;
        f32x4 acc[8] = {z4, z4, z4, z4, z4, z4, z4, z4};
        bf8_t a0F = *(const bf8_t*)(arow0);
        bf8_t a1F = *(const bf8_t*)(arow1);
        bf8_t bF[4];
        #pragma unroll
        for (int j = 0; j < 4; j++) bF[j] = *(const bf8_t*)(brow[j]);
        #pragma unroll
        for (int it = 0; it < D/32; it++){
            bf8_t a0C = a0F, a1C = a1F;
            bf8_t bC[4] = {bF[0], bF[1], bF[2], bF[3]};
            if (it + 1 < D/32){
                int kn = (it + 1)*32;
                a0F = *(const bf8_t*)(arow0 + kn);
                a1F = *(const bf8_t*)(arow1 + kn);
                #pragma unroll
                for (int j = 0; j < 4; j++) bF[j] = *(const bf8_t*)(brow[j] + kn);
            }
            #pragma unroll
            for (int j = 0; j < 4; j++){
                acc[j]   = __builtin_amdgcn_mfma_f32_16x16x32_bf16(a0C, bC[j], acc[j],   0, 0, 0);
                acc[4+j] = __builtin_amdgcn_mfma_f32_16x16x32_bf16(a1C, bC[j], acc[4+j], 0, 0, 0);
            }
        }
        int mbase0 = m0 + wave*16 + quad*4;
        int mbase1 = mbase0 + 64;
        float bias0[4], bias1[4];
        #pragma unroll
        for (int r = 0; r < 4; r++){ bias0[r] = pp.blend_b[mbase0 + r]; bias1[r] = pp.blend_b[mbase1 + r]; }
        float lsum = 0.f;
        #pragma unroll
        for (int j = 0; j < 4; j++){
            int rown = n0 + j*16 + l16;
            f32x4 st0, st1;
            #pragma unroll
            for (int r = 0; r < 4; r++){
                float g0 = 1.f/(1.f + __expf(-(acc[j][r] + bias0[r])));
                float g1 = 1.f/(1.f + __expf(-(acc[4+j][r] + bias1[r])));
                lsum += g0 + g1;
                st0[r] = g0; st1[r] = g1;
            }
            *(f32x4*)(pp.gatebuf + (size_t)rown*D + mbase0) = st0;
            *(f32x4*)(pp.gatebuf + (size_t)rown*D + mbase1) = st1;
        }
        float* redp = &ep[0][0][0][0];
        redp[tid] = lsum;
        __syncthreads();
        for (int sft = 128; sft; sft >>= 1){
            if (tid < sft) redp[tid] += redp[tid + sft];
            __syncthreads();
        }
        if (tid == 0 && rep == 0) atomicAdd(pp.sumBuf, redp[0]);
    } else {
        // ---- expert slice: head pair p -> heads 2p, 2p+1 ----
        int p = blockIdx.x;
        int m0 = p*128;
        const unsigned short* arow0 = pp.w1nk + (size_t)e*HHD*D + (size_t)(m0 + wave*16 + l16)*D + quad*8;
        const unsigned short* arow1 = arow0 + (size_t)64*D;
        const unsigned short* brow[4];
        bool zr[4];
        #pragma unroll
        for (int j = 0; j < 4; j++){
            int n = n0 + j*16 + l16;
            brow[j] = pp.featbf + (size_t)n*D + quad*8;
            zr[j] = (e > 0) ? (pp.rmask[(size_t)(e-1)*ROWS + n] == 0.f) : false;
        }
        f32x4 acc[8] = {z4, z4, z4, z4, z4, z4, z4, z4};
        bf8_t a0F = *(const bf8_t*)(arow0);
        bf8_t a1F = *(const bf8_t*)(arow1);
        bf8_t bF[4];
        #pragma unroll
        for (int j = 0; j < 4; j++) bF[j] = zr[j] ? bz : *(const bf8_t*)(brow[j]);
        #pragma unroll
        for (int it = 0; it < D/32; it++){
            bf8_t a0C = a0F, a1C = a1F;
            bf8_t bC[4] = {bF[0], bF[1], bF[2], bF[3]};
            if (it + 1 < D/32){
                int kn = (it + 1)*32;
                a0F = *(const bf8_t*)(arow0 + kn);
                a1F = *(const bf8_t*)(arow1 + kn);
                #pragma unroll
                for (int j = 0; j < 4; j++) bF[j] = zr[j] ? bz : *(const bf8_t*)(brow[j] + kn);
            }
            #pragma unroll
            for (int j = 0; j < 4; j++){
                acc[j]   = __builtin_amdgcn_mfma_f32_16x16x32_bf16(a0C, bC[j], acc[j],   0, 0, 0);
                acc[4+j] = __builtin_amdgcn_mfma_f32_16x16x32_bf16(a1C, bC[j], acc[4+j], 0, 0, 0);
            }
        }
        int b = n0 >> 10;
        int mbase0 = m0 + wave*16 + quad*4;
        int mbase1 = mbase0 + 64;
        int obase = wave*16 + quad*4;   // o within head (0..63)
        int h0 = p*2, h1 = p*2 + 1;
        // packed store: u32 = (head 2p | head 2p+1 << 16) at [row][p*64 + o]
        unsigned int* hp4 = (unsigned int*)pp.htn4;
        #pragma unroll
        for (int j = 0; j < 4; j++){
            int row = n0 + j*16 + l16;
            uint4 ov;
            ov.x = (unsigned)f2bf(acc[j][0]) | ((unsigned)f2bf(acc[4+j][0]) << 16);
            ov.y = (unsigned)f2bf(acc[j][1]) | ((unsigned)f2bf(acc[4+j][1]) << 16);
            ov.z = (unsigned)f2bf(acc[j][2]) | ((unsigned)f2bf(acc[4+j][2]) << 16);
            ov.w = (unsigned)f2bf(acc[j][3]) | ((unsigned)f2bf(acc[4+j][3]) << 16);
            *(uint4*)(hp4 + ((size_t)e*ROWS + row)*192 + p*64 + obase) = ov;
        }
        const float* a1sp = (e == 0) ? pp.main_a1s : pp.dep_a1s + (size_t)(e-1)*H*HD;
        const float* a1dp = (e == 0) ? pp.main_a1d : pp.dep_a1d + (size_t)(e-1)*H*HD;
        float s0v[4], d0v[4], s1v[4], d1v[4];
        #pragma unroll
        for (int r = 0; r < 4; r++){
            s0v[r] = a1sp[mbase0 + r]; d0v[r] = a1dp[mbase0 + r];
            s1v[r] = a1sp[mbase1 + r]; d1v[r] = a1dp[mbase1 + r];
        }
        #pragma unroll
        for (int j = 0; j < 4; j++){
            float ps0 = 0.f, pd0 = 0.f, ps1 = 0.f, pd1 = 0.f;
            #pragma unroll
            for (int r = 0; r < 4; r++){
                ps0 += acc[j][r]*s0v[r];   pd0 += acc[j][r]*d0v[r];
                ps1 += acc[4+j][r]*s1v[r]; pd1 += acc[4+j][r]*d1v[r];
            }
            ep[0][0][j*16 + l16][wave*4 + quad] = ps0;
            ep[0][1][j*16 + l16][wave*4 + quad] = pd0;
            ep[1][0][j*16 + l16][wave*4 + quad] = ps1;
            ep[1][1][j*16 + l16][wave*4 + quad] = pd1;
        }
        float* mvb = pp.meanV1p + ((size_t)e*B + b)*512;
        #pragma unroll
        for (int r = 0; r < 4; r++){
            float cm0 = acc[0][r] + acc[1][r] + acc[2][r] + acc[3][r];
            float cm1 = acc[4][r] + acc[5][r] + acc[6][r] + acc[7][r];
            for (int off = 8; off; off >>= 1){
                cm0 += __shfl_down(cm0, off, 16);
                cm1 += __shfl_down(cm1, off, 16);
            }
            if (l16 == 0 && rep == 0){
                atomicAdd(mvb + (obase + r)*8 + h0, cm0*(1.f/(float)S));
                atomicAdd(mvb + (obase + r)*8 + h1, cm1*(1.f/(float)S));
            }
        }
        __syncthreads();
        {
            int hh = tid >> 7, arr = (tid >> 6) & 1, sl = tid & 63;
            float sum = 0.f;
            #pragma unroll
            for (int i = 0; i < 16; i++) sum += ep[hh][arr][sl][i];
            int n = n0 + sl;
            float* dst = arr ? pp.ed8 : pp.es8;
            dst[(((size_t)e*B + (n >> 10))*S + (n & 1023))*8 + (p*2 + hh)] = sum;
        }
    }
    __syncthreads();
    }
}

// ---------- attn1 gather: 4-wave split per (e,b,s); packed htn4 reads (3 loads/neighbor) ----------
// grid (S, 16), 256 threads
__global__ __launch_bounds__(256) void a1_kernel(P pp)
{
    __shared__ float wrec[MAXN][8];    // 4 KB
    __shared__ float pacc[3][64][8];   // 6 KB
    __shared__ float pden[2][8];
    int tid = threadIdx.x;
    int wave = tid >> 6, lane = tid & 63;
    int s = blockIdx.x;
    int e = blockIdx.y >> 2, b = blockIdx.y & 3;
    int row = b*S + s;
    int4 c = pp.nbc[row];
    int lo = 0, hi = c.x;
    if (e == 1) hi = c.y;
    else if (e == 2){ lo = c.y; hi = c.z; }
    else if (e == 3){ lo = c.z; }
    int nn = hi - lo;
    const short* nl = pp.nbr + (size_t)row*MAXN;

    #pragma unroll 1
    for (int rep = 0; rep < REP; rep++){
    if (wave < 2){
        const float* esp = pp.es8 + (((size_t)e*B + b)*S + s)*8;
        f32x4 es_lo = *(const f32x4*)esp;
        f32x4 es_hi = *(const f32x4*)(esp + 4);
        float esv[6] = {es_lo[0], es_lo[1], es_lo[2], es_lo[3], es_hi[0], es_hi[1]};
        const float* edb = pp.ed8 + ((size_t)e*B + b)*S*8;
        int i = wave*64 + lane;
        float w[6] = {0,0,0,0,0,0};
        if (i < nn){
            int t = nl[lo + i];
            const float* epn = edb + (size_t)t*8;
            f32x4 d0 = *(const f32x4*)epn;
            f32x4 d1 = *(const f32x4*)(epn + 4);
            float edv[6] = {d0[0], d0[1], d0[2], d0[3], d1[0], d1[1]};
            #pragma unroll
            for (int h = 0; h < 6; h++) w[h] = __expf(leaky(esv[h] + edv[h]));
            // deputy neighbors with rmask==0 have exactly-zero V rows: skip their gather
            float zf = 0.f;
            if (e > 0 && pp.rmask[(size_t)(e-1)*ROWS + (size_t)b*S + t] == 0.f) zf = 1.f;
            f32x4 r0 = {w[0], w[1], w[2], w[3]};
            f32x4 r1 = {w[4], w[5], i2f(t), zf};
            *(f32x4*)&wrec[i][0] = r0;
            *(f32x4*)&wrec[i][4] = r1;
        }
        #pragma unroll
        for (int h = 0; h < 6; h++){
            float x = w[h];
            for (int o2 = 32; o2; o2 >>= 1) x += __shfl_down(x, o2);
            if (lane == 0) pden[wave][h] = x;
        }
    }
    __syncthreads();
    const unsigned int* Vb = (const unsigned int*)pp.htn4 + ((size_t)e*ROWS + b*S)*192 + lane;
    float acc[6] = {0,0,0,0,0,0};
    #pragma unroll 2
    for (int j = wave; j < nn; j += 4){
        f32x4 r0 = *(const f32x4*)&wrec[j][0];
        f32x4 r1 = *(const f32x4*)&wrec[j][4];
        if (r1[3] != 0.f) continue;            // V row exactly zero
        int t = f2i(r1[2]);
        const unsigned int* vp = Vb + (size_t)t*192;
        unsigned int u0 = vp[0];
        unsigned int u1 = vp[64];
        unsigned int u2 = vp[128];
        acc[0] += r0[0]*blo(u0); acc[1] += r0[1]*bhi(u0);
        acc[2] += r0[2]*blo(u1); acc[3] += r0[3]*bhi(u1);
        acc[4] += r1[0]*blo(u2); acc[5] += r1[1]*bhi(u2);
    }
    if (wave >= 1){
        float* pb = &pacc[wave-1][lane][0];
        f32x4 p0 = {acc[0], acc[1], acc[2], acc[3]};
        f32x4 p1 = {acc[4], acc[5], 0.f, 0.f};
        *(f32x4*)pb = p0;
        *(f32x4*)(pb + 4) = p1;
    }
    __syncthreads();
    if (wave == 0){
        unsigned short* outp = pp.h1c4 + ((size_t)e*ROWS + row)*HHD;
        const float* mv = pp.meanV1p + ((size_t)e*B + b)*512 + lane*8;
        #pragma unroll
        for (int h = 0; h < 6; h++){
            float den = pden[0][h] + pden[1][h];
            float v = (nn > 0) ? (acc[h] + pacc[0][lane][h] + pacc[1][lane][h] + pacc[2][lane][h])/den
                               : mv[h];
            v = v > 0.f ? v : __expf(v) - 1.f;   // ELU
            outp[h*64 + lane] = f2bf(v);
        }
    }
    __syncthreads();
    }
}

// ---------- GEMM2 (h1@W2) + fused f2s/f2d + colmean ----------
// grid (D/128=2, ROWS/64, 4)
__global__ __launch_bounds__(256, 4) void gemm2_kernel(P pp)
{
    __shared__ float ep[2][2][64][17];
    int tid = threadIdx.x, wave = tid >> 6, lane = tid & 63;
    int quad = lane >> 4, l16 = lane & 15;
    int e = blockIdx.z;
    int m0 = blockIdx.x*128;
    int n0 = blockIdx.y*64;
    f32x4 z4 = {0.f,0.f,0.f,0.f};

    #pragma unroll 1
    for (int rep = 0; rep < REP; rep++){
    const unsigned short* arow0 = pp.w2nk + (size_t)e*D*HHD + (size_t)(m0 + wave*16 + l16)*HHD + quad*8;
    const unsigned short* arow1 = arow0 + (size_t)64*HHD;
    const unsigned short* brow[4];
    #pragma unroll
    for (int j = 0; j < 4; j++)
        brow[j] = pp.h1c4 + (size_t)e*ROWS*HHD + (size_t)(n0 + j*16 + l16)*HHD + quad*8;
    f32x4 acc[8] = {z4, z4, z4, z4, z4, z4, z4, z4};
    bf8_t a0F = *(const bf8_t*)(arow0);
    bf8_t a1F = *(const bf8_t*)(arow1);
    bf8_t bF[4];
    #pragma unroll
    for (int j = 0; j < 4; j++) bF[j] = *(const bf8_t*)(brow[j]);
    #pragma unroll
    for (int it = 0; it < HHD/32; it++){
        bf8_t a0C = a0F, a1C = a1F;
        bf8_t bC[4] = {bF[0], bF[1], bF[2], bF[3]};
        if (it + 1 < HHD/32){
            int kn = (it + 1)*32;
            a0F = *(const bf8_t*)(arow0 + kn);
            a1F = *(const bf8_t*)(arow1 + kn);
            #pragma unroll
            for (int j = 0; j < 4; j++) bF[j] = *(const bf8_t*)(brow[j] + kn);
        }
        #pragma unroll
        for (int j = 0; j < 4; j++){
            acc[j]   = __builtin_amdgcn_mfma_f32_16x16x32_bf16(a0C, bC[j], acc[j],   0, 0, 0);
            acc[4+j] = __builtin_amdgcn_mfma_f32_16x16x32_bf16(a1C, bC[j], acc[4+j], 0, 0, 0);
        }
    }
    int b = n0 >> 10;
    int mbase0 = m0 + wave*16 + quad*4;
    int mbase1 = mbase0 + 64;
    #pragma unroll
    for (int j = 0; j < 4; j++){
        int row = n0 + j*16 + l16;
        ushort4 o0, o1;
        o0.x = f2bf(acc[j][0]);   o0.y = f2bf(acc[j][1]);
        o0.z = f2bf(acc[j][2]);   o0.w = f2bf(acc[j][3]);
        o1.x = f2bf(acc[4+j][0]); o1.y = f2bf(acc[4+j][1]);
        o1.z = f2bf(acc[4+j][2]); o1.w = f2bf(acc[4+j][3]);
        *(ushort4*)(pp.h2n4 + ((size_t)e*ROWS + row)*D + mbase0) = o0;
        *(ushort4*)(pp.h2n4 + ((size_t)e*ROWS + row)*D + mbase1) = o1;
    }
    const float* a2sp = (e == 0) ? pp.main_a2s : pp.dep_a2s + (size_t)(e-1)*D;
    const float* a2dp = (e == 0) ? pp.main_a2d : pp.dep_a2d + (size_t)(e-1)*D;
    float s0v[4], d0v[4], s1v[4], d1v[4];
    #pragma unroll
    for (int r = 0; r < 4; r++){
        s0v[r] = a2sp[mbase0 + r]; d0v[r] = a2dp[mbase0 + r];
        s1v[r] = a2sp[mbase1 + r]; d1v[r] = a2dp[mbase1 + r];
    }
    #pragma unroll
    for (int j = 0; j < 4; j++){
        float ps0 = 0.f, pd0 = 0.f, ps1 = 0.f, pd1 = 0.f;
        #pragma unroll
        for (int r = 0; r < 4; r++){
            ps0 += acc[j][r]*s0v[r];   pd0 += acc[j][r]*d0v[r];
            ps1 += acc[4+j][r]*s1v[r]; pd1 += acc[4+j][r]*d1v[r];
        }
        ep[0][0][j*16 + l16][wave*4 + quad] = ps0;
        ep[0][1][j*16 + l16][wave*4 + quad] = pd0;
        ep[1][0][j*16 + l16][wave*4 + quad] = ps1;
        ep[1][1][j*16 + l16][wave*4 + quad] = pd1;
    }
    #pragma unroll
    for (int r = 0; r < 4; r++){
        float cm0 = acc[0][r] + acc[1][r] + acc[2][r] + acc[3][r];
        float cm1 = acc[4][r] + acc[5][r] + acc[6][r] + acc[7][r];
        for (int off = 8; off; off >>= 1){
            cm0 += __shfl_down(cm0, off, 16);
            cm1 += __shfl_down(cm1, off, 16);
        }
        if (l16 == 0 && rep == 0){
            atomicAdd(pp.meanV2 + ((size_t)e*B + b)*D + mbase0 + r, cm0*(1.f/(float)S));
            atomicAdd(pp.meanV2 + ((size_t)e*B + b)*D + mbase1 + r, cm1*(1.f/(float)S));
        }
    }
    __syncthreads();
    {
        int hh = tid >> 7, arr = (tid >> 6) & 1, sl = tid & 63;
        float sum = 0.f;
        #pragma unroll
        for (int i = 0; i < 16; i++) sum += ep[hh][arr][sl][i];
        int n = n0 + sl;
        float* dst = arr ? pp.f2d4 : pp.f2s4;
        if (rep == 0) atomicAdd(dst + (size_t)e*ROWS + n, sum);
    }
    __syncthreads();
    }
}

// ---------- attn2 + blend: waves 0,1 main; waves 2,3 active deputies ----------
// grid (S, B), 256 threads
__global__ __launch_bounds__(256) void a2_kernel(P pp)
{
    __shared__ float2 wrec0[MAXN];
    __shared__ float2 wrec1[MAXN];
    __shared__ float pacc[3][256];
    __shared__ float pden[4][4];
    int tid = threadIdx.x;
    int wave = tid >> 6, lane = tid & 63;
    int s = blockIdx.x, b = blockIdx.y;
    int row = b*S + s;
    int4 c = pp.nbc[row];
    float rm0 = pp.rmask[row], rm1 = pp.rmask[ROWS + row], rm2 = pp.rmask[2*ROWS + row];
    const short* nl = pp.nbr + (size_t)row*MAXN;

    #pragma unroll 1
    for (int rep = 0; rep < REP; rep++){
    // ---- weight phase ----
    if (wave < 2){
        int i = wave*64 + lane;
        float w = 0.f;
        if (i < c.x){
            int t = nl[i];
            float fs = pp.f2s4[row];
            w = __expf(leaky(fs + pp.f2d4[(size_t)b*S + t]));
            float2 r; r.x = w; r.y = i2f(t);
            wrec0[i] = r;
        }
        float dsum = w;
        for (int o2 = 32; o2; o2 >>= 1) dsum += __shfl_down(dsum, o2);
        if (lane == 0) pden[wave][0] = dsum;
    } else {
        int i = (wave - 2)*64 + lane;
        float w = 0.f, d1 = 0.f, d2 = 0.f, d3 = 0.f;
        if (i < c.x){
            int t = nl[i];
            int tag = (i < c.y) ? 1 : ((i < c.z) ? 2 : 3);
            float act = (tag == 1) ? rm0 : ((tag == 2) ? rm1 : rm2);
            if (act != 0.f){
                float fs = pp.f2s4[(size_t)tag*ROWS + row];
                w = __expf(leaky(fs + pp.f2d4[(size_t)tag*ROWS + (size_t)b*S + t]));
            }
            float2 r; r.x = w; r.y = i2f(t);
            wrec1[i] = r;
            if (tag == 1) d1 = w; else if (tag == 2) d2 = w; else d3 = w;
        }
        for (int o2 = 32; o2; o2 >>= 1){
            d1 += __shfl_down(d1, o2);
            d2 += __shfl_down(d2, o2);
            d3 += __shfl_down(d3, o2);
        }
        if (lane == 0){ pden[wave][1] = d1; pden[wave][2] = d2; pden[wave][3] = d3; }
    }
    __syncthreads();
    // ---- gather phase ----
    float acc[4] = {0.f, 0.f, 0.f, 0.f};
    if (wave < 2){
        float inv = 1.f/(pden[0][0] + pden[1][0]);   // c.x >= 1 (self-loop) always
        const unsigned short* V = pp.h2n4 + (size_t)b*S*D;
        #pragma unroll 4
        for (int j = wave; j < c.x; j += 2){
            float2 r = wrec0[j];
            float wv = r.x*inv;
            int t = f2i(r.y);
            const unsigned short* vp = V + (size_t)t*D + lane*4;
            uint2 dv = *(const uint2*)vp;
            acc[0] += wv*blo(dv.x); acc[1] += wv*bhi(dv.x);
            acc[2] += wv*blo(dv.y); acc[3] += wv*bhi(dv.y);
        }
    } else {
        int rlo[3] = {0, c.y, c.z};
        int rhi[3] = {c.y, c.z, c.x};
        float ract[3] = {rm0, rm1, rm2};
        for (int rg = 0; rg < 3; rg++){
            if (ract[rg] == 0.f || rhi[rg] <= rlo[rg]) continue;
            float inv = 1.f/(pden[2][rg+1] + pden[3][rg+1]);
            const unsigned short* V = pp.h2n4 + ((size_t)(rg+1)*ROWS + (size_t)b*S)*D;
            #pragma unroll 4
            for (int j = rlo[rg] + (wave - 2); j < rhi[rg]; j += 2){
                float2 r = wrec1[j];
                float wv = r.x*inv;
                int t = f2i(r.y);
                const unsigned short* vp = V + (size_t)t*D + lane*4;
                uint2 dv = *(const uint2*)vp;
                acc[0] += wv*blo(dv.x); acc[1] += wv*bhi(dv.x);
                acc[2] += wv*blo(dv.y); acc[3] += wv*bhi(dv.y);
            }
        }
    }
    if (wave >= 1){
        #pragma unroll
        for (int q = 0; q < 4; q++) pacc[wave-1][lane*4 + q] = acc[q];
    }
    __syncthreads();
    // ---- combine + blend (wave 0) ----
    if (wave == 0){
        float4 g4 = *(const float4*)(pp.gatebuf + (size_t)row*D + lane*4);
        float dep_mv[4] = {0.f, 0.f, 0.f, 0.f};
        if (rm0 != 0.f && c.y == 0){
            float4 mv = *(const float4*)(pp.meanV2 + ((size_t)1*B + b)*D + lane*4);
            dep_mv[0] += mv.x; dep_mv[1] += mv.y; dep_mv[2] += mv.z; dep_mv[3] += mv.w;
        }
        if (rm1 != 0.f && c.z == c.y){
            float4 mv = *(const float4*)(pp.meanV2 + ((size_t)2*B + b)*D + lane*4);
            dep_mv[0] += mv.x; dep_mv[1] += mv.y; dep_mv[2] += mv.z; dep_mv[3] += mv.w;
        }
        if (rm2 != 0.f && c.x == c.z){
            float4 mv = *(const float4*)(pp.meanV2 + ((size_t)3*B + b)*D + lane*4);
            dep_mv[0] += mv.x; dep_mv[1] += mv.y; dep_mv[2] += mv.z; dep_mv[3] += mv.w;
        }
        float g[4] = {g4.x, g4.y, g4.z, g4.w};
        float4 o;
        float* op = &o.x;
        #pragma unroll
        for (int q = 0; q < 4; q++){
            int col = lane*4 + q;
            float a0 = acc[q] + pacc[0][col];
            float dep = pacc[1][col] + pacc[2][col] + dep_mv[q];
            op[q] = g[q]*a0 + (1.f - g[q])*dep;
        }
        *(float4*)(pp.outp + (size_t)row*D + lane*4) = o;
    }
    if (blockIdx.x == 0 && blockIdx.y == 0 && tid == 0){
        float mc = pp.sumBuf[0] / (float)(ROWS*D);
        pp.outp[ROWS*D]     = fabsf(mc - 0.6f)*0.01f;
        pp.outp[ROWS*D + 1] = mc;
    }
    __syncthreads();
    }
}

extern "C" void kernel_launch(void* const* d_in, const int* in_sizes, int n_in,
                              void* d_out, int out_size, void* d_ws, size_t ws_size,
                              hipStream_t stream)
{
    P hp;
    hp.feature  = (const float*)d_in[0];
    hp.adj      = (const float*)d_in[1];
    hp.main_W1  = (const float*)d_in[2];
    hp.main_a1s = (const float*)d_in[3];
    hp.main_a1d = (const float*)d_in[4];
    hp.main_W2  = (const float*)d_in[5];
    hp.main_a2s = (const float*)d_in[6];
    hp.main_a2d = (const float*)d_in[7];
    hp.dep_W1   = (const float*)d_in[8];
    hp.dep_a1s  = (const float*)d_in[9];
    hp.dep_a1d  = (const float*)d_in[10];
    hp.dep_W2   = (const float*)d_in[11];
    hp.dep_a2s  = (const float*)d_in[12];
    hp.dep_a2d  = (const float*)d_in[13];
    hp.router_W = (const float*)d_in[14];
    hp.blend_W  = (const float*)d_in[15];
    hp.blend_b  = (const float*)d_in[16];
    hp.doc_p    = (const int*)d_in[17];
    hp.sect_p   = (const int*)d_in[18];

    char* ws = (char*)d_ws;
    size_t off = 0;
    hp.featbf = (unsigned short*)(ws + off); off += (size_t)ROWS*D*2;        // 2 MB
    hp.nbr    = (short*)(ws + off);          off += (size_t)ROWS*MAXN*2;     // 1 MB
    hp.nbc    = (int4*)(ws + off);           off += (size_t)ROWS*16;         // 64 KB
    hp.w1nk   = (unsigned short*)(ws + off); off += (size_t)4*HHD*D*2;
    hp.w2nk   = (unsigned short*)(ws + off); off += (size_t)4*D*HHD*2;
    hp.bwt    = (unsigned short*)(ws + off); off += (size_t)D*D*2;
    hp.es8 = (float*)(ws + off); off += (size_t)4*B*S*8*4;   // 512 KB
    hp.ed8 = (float*)(ws + off); off += (size_t)4*B*S*8*4;   // 512 KB
    hp.gatebuf = (float*)(ws + off); off += (size_t)ROWS*D*4;                // 4 MB
    hp.htn4 = (unsigned short*)(ws + off); off += (size_t)4*ROWS*HHD*2;      // 12 MB (packed u32 layout, same bytes)
    hp.h2n4 = (unsigned short*)(ws + off); off += (size_t)4*ROWS*D*2;        // 8 MB
    hp.h1c4 = (unsigned short*)(ws + off); off += (size_t)4*ROWS*HHD*2;      // 12 MB
    // contiguous zero region (NZERO floats) starts at f2s4:
    hp.f2s4    = (float*)(ws + off); off += (size_t)4*ROWS*4;
    hp.f2d4    = (float*)(ws + off); off += (size_t)4*ROWS*4;
    hp.meanV1p = (float*)(ws + off); off += (size_t)4*B*512*4;
    hp.meanV2  = (float*)(ws + off); off += (size_t)4*B*D*4;
    hp.sumBuf  = (float*)(ws + off); off += 128;
    hp.rmask   = (float*)(ws + off); off += (size_t)NE*ROWS*4;
    hp.outp    = (float*)d_out;

    prep_kernel<<<PB_TOTAL, 256, 0, stream>>>(hp);
    gemm1_kernel<<<dim3(3, ROWS/64, 5), 256, 0, stream>>>(hp);
    a1_kernel<<<dim3(S, 16), 256, 0, stream>>>(hp);
    gemm2_kernel<<<dim3(D/128, ROWS/64, 4), 256, 0, stream>>>(hp);
    a2_kernel<<<dim3(S, B), 256, 0, stream>>>(hp);
}

// Round 4
// 225.976 us; speedup vs baseline: 3.6321x; 1.5449x over previous
//
#include <hip/hip_runtime.h>
#include <math.h>

#define B 4
#define S 1024
#define D 256
#define H 6
#define HD 64
#define NE 3
#define HHD 384
#define ROWS (B*S)
#define MAXN 128

typedef __attribute__((ext_vector_type(8))) short bf8_t;
typedef __attribute__((ext_vector_type(4))) float f32x4;

__device__ __forceinline__ float leaky(float x){ return x > 0.f ? x : 0.2f*x; }

__device__ __forceinline__ unsigned short f2bf(float f){
    union { float f; unsigned int u; } v; v.f = f;
    unsigned int u = v.u;
    return (unsigned short)((u + 0x7FFFu + ((u >> 16) & 1u)) >> 16);
}
__device__ __forceinline__ float bf2f(unsigned short h){
    union { unsigned int u; float f; } v; v.u = ((unsigned int)h) << 16;
    return v.f;
}
__device__ __forceinline__ float blo(unsigned int u){
    union { unsigned int u; float f; } v; v.u = u << 16; return v.f;
}
__device__ __forceinline__ float bhi(unsigned int u){
    union { unsigned int u; float f; } v; v.u = u & 0xffff0000u; return v.f;
}
__device__ __forceinline__ float i2f(int t){
    union { int i; float f; } v; v.i = t; return v.f;
}
__device__ __forceinline__ int f2i(float f){
    union { float f; int i; } v; v.f = f; return v.i;
}
__device__ __forceinline__ unsigned int pk2(float lo, float hi){
    return (unsigned)f2bf(lo) | ((unsigned)f2bf(hi) << 16);
}

// ---------- params ----------
struct P {
    const float *feature, *adj;
    const float *main_W1, *dep_W1, *main_W2, *dep_W2, *blend_W, *router_W;
    const int *doc_p, *sect_p;
    const float *main_a1s, *main_a1d, *dep_a1s, *dep_a1d;
    const float *main_a2s, *main_a2d, *dep_a2s, *dep_a2d;
    const float *blend_b;
    unsigned short *featbf; short *nbr; int4 *nbc;
    unsigned short *w1nk, *w2nk, *bwt;
    float *es8, *ed8, *gatebuf;
    unsigned short *htn4, *h2n4, *h1c4;
    float *f2s4, *f2d4, *meanV1p, *meanV2, *sumBuf, *rmask;
    float *outp;
};

// ---------- block ranges for prep ----------
#define PB_CONV   1024
#define PB_NBR    1024
#define PB_W1     1536
#define PB_W2     1536
#define PB_BW      256
#define PB_ZERO    177
#define PB_ROUTER 1024
#define PB_TOTAL  (PB_CONV + PB_NBR + PB_W1 + PB_W2 + PB_BW + PB_ZERO + PB_ROUTER)
#define NZERO     45088

__global__ __launch_bounds__(256) void prep_kernel(P pp)
{
    int blk = blockIdx.x, tid = threadIdx.x;
    if (blk < PB_CONV){
        int idx = blk*256 + tid;                       // < ROWS*D/4
        float4 v = ((const float4*)pp.feature)[idx];
        ushort4 o;
        o.x = f2bf(v.x); o.y = f2bf(v.y); o.z = f2bf(v.z); o.w = f2bf(v.w);
        ((ushort4*)pp.featbf)[idx] = o;
        return;
    }
    blk -= PB_CONV;
    if (blk < PB_NBR){
        int wave = tid >> 6, lane = tid & 63;
        int row = blk*4 + wave;
        int b1 = S - *pp.sect_p - *pp.doc_p;
        int b2 = S - *pp.doc_p;
        const float* ar = pp.adj + (size_t)row*S + lane*16;
        float a[16];
        #pragma unroll
        for (int q = 0; q < 4; q++){
            float4 v = ((const float4*)ar)[q];
            a[q*4+0] = v.x; a[q*4+1] = v.y; a[q*4+2] = v.z; a[q*4+3] = v.w;
        }
        int t0 = lane*16;
        int k = 0, c1 = 0, c2 = 0;
        #pragma unroll
        for (int i = 0; i < 16; i++){
            if (a[i] > 0.f){
                k++;
                int t = t0 + i;
                if (t < b1) c1++;
                if (t < b2) c2++;
            }
        }
        int inc = k;
        #pragma unroll
        for (int d = 1; d < 64; d <<= 1){
            int u = __shfl_up(inc, d);
            if (lane >= d) inc += u;
        }
        int off = inc - k;
        int total = __shfl(inc, 63);
        int o = row*MAXN + off;
        #pragma unroll
        for (int i = 0; i < 16; i++){
            if (a[i] > 0.f) pp.nbr[o++] = (short)(t0 + i);
        }
        for (int d = 32; d; d >>= 1){
            c1 += __shfl_down(c1, d);
            c2 += __shfl_down(c2, d);
        }
        if (lane == 0) pp.nbc[row] = make_int4(total, c1, c2, 0);
        return;
    }
    blk -= PB_NBR;
    if (blk < PB_W1){
        int e = blk / 384;
        int idx = (blk - e*384)*256 + tid;             // < HHD*D
        const float* src = (e == 0) ? pp.main_W1 : pp.dep_W1 + (size_t)(e-1)*H*D*HD;
        int n = idx >> 8, k = idx & 255;
        int h = n >> 6, o = n & 63;
        pp.w1nk[(size_t)e*HHD*D + idx] = f2bf(src[(h*D + k)*HD + o]);
        return;
    }
    blk -= PB_W1;
    if (blk < PB_W2){
        int g = blk*256 + tid;                         // < 4*D*HHD
        int e = g / (D*HHD);
        int rem = g - e*(D*HHD);
        int n = rem / HHD, k = rem - n*HHD;
        const float* src = (e == 0) ? pp.main_W2 : pp.dep_W2 + (size_t)(e-1)*HHD*D;
        pp.w2nk[g] = f2bf(src[k*D + n]);
        return;
    }
    blk -= PB_W2;
    if (blk < PB_BW){
        int col = blk, k = tid;
        pp.bwt[col*D + k] = f2bf(pp.blend_W[k*D + col]);
        return;
    }
    blk -= PB_BW;
    if (blk < PB_ZERO){
        int idx = blk*256 + tid;
        if (idx < NZERO) pp.f2s4[idx] = 0.f;           // contiguous zero region base
        return;
    }
    blk -= PB_ZERO;
    {
        int wave = tid >> 6, lane = tid & 63;
        int row = blk*4 + wave;
        float4 xv = ((const float4*)(pp.feature + (size_t)row*D))[lane];
        int f = lane*4;
        float xa[4] = {xv.x, xv.y, xv.z, xv.w};
        float p0 = 0.f, p1 = 0.f, p2 = 0.f;
        #pragma unroll
        for (int j = 0; j < 4; j++){
            p0 += xa[j]*pp.router_W[(f+j)*NE + 0];
            p1 += xa[j]*pp.router_W[(f+j)*NE + 1];
            p2 += xa[j]*pp.router_W[(f+j)*NE + 2];
        }
        for (int off = 32; off; off >>= 1){
            p0 += __shfl_down(p0, off);
            p1 += __shfl_down(p1, off);
            p2 += __shfl_down(p2, off);
        }
        if (lane == 0){
            float p[3] = {p0, p1, p2};
            int ex = 0;
            for (int e = 1; e < NE; e++) if (p[e] <= p[ex]) ex = e;
            for (int e = 0; e < NE; e++) pp.rmask[e*ROWS + row] = (e == ex) ? 0.f : 1.f;
        }
    }
}

// ---------- GEMM1 (x@W1) + fused es/ed + colmean; htn4 stored [row][o][pair,pad] ----------
// grid (3, ROWS/64, 5). z<4: expert slices; z==4: blend gate (x<2).
__global__ __launch_bounds__(256, 4) void gemm1_kernel(P pp)
{
    __shared__ float ep[2][2][64][17];      // 17408 B
    int tid = threadIdx.x, wave = tid >> 6, lane = tid & 63;
    int quad = lane >> 4, l16 = lane & 15;
    int e = blockIdx.z;
    int n0 = blockIdx.y*64;
    f32x4 z4 = {0.f,0.f,0.f,0.f};
    bf8_t bz = {0,0,0,0,0,0,0,0};

    if (e == 4){
        // ---- blend gate GEMM ----
        if (blockIdx.x >= 2) return;
        int m0 = blockIdx.x*128;
        const unsigned short* arow0 = pp.bwt + (size_t)(m0 + wave*16 + l16)*D + quad*8;
        const unsigned short* arow1 = arow0 + (size_t)64*D;
        const unsigned short* brow[4];
        #pragma unroll
        for (int j = 0; j < 4; j++)
            brow[j] = pp.featbf + (size_t)(n0 + j*16 + l16)*D + quad*8;
        f32x4 acc[8] = {z4, z4, z4, z4, z4, z4, z4, z4};
        bf8_t a0F = *(const bf8_t*)(arow0);
        bf8_t a1F = *(const bf8_t*)(arow1);
        bf8_t bF[4];
        #pragma unroll
        for (int j = 0; j < 4; j++) bF[j] = *(const bf8_t*)(brow[j]);
        #pragma unroll
        for (int it = 0; it < D/32; it++){
            bf8_t a0C = a0F, a1C = a1F;
            bf8_t bC[4] = {bF[0], bF[1], bF[2], bF[3]};
            if (it + 1 < D/32){
                int kn = (it + 1)*32;
                a0F = *(const bf8_t*)(arow0 + kn);
                a1F = *(const bf8_t*)(arow1 + kn);
                #pragma unroll
                for (int j = 0; j < 4; j++) bF[j] = *(const bf8_t*)(brow[j] + kn);
            }
            #pragma unroll
            for (int j = 0; j < 4; j++){
                acc[j]   = __builtin_amdgcn_mfma_f32_16x16x32_bf16(a0C, bC[j], acc[j],   0, 0, 0);
                acc[4+j] = __builtin_amdgcn_mfma_f32_16x16x32_bf16(a1C, bC[j], acc[4+j], 0, 0, 0);
            }
        }
        int mbase0 = m0 + wave*16 + quad*4;
        int mbase1 = mbase0 + 64;
        float bias0[4], bias1[4];
        #pragma unroll
        for (int r = 0; r < 4; r++){ bias0[r] = pp.blend_b[mbase0 + r]; bias1[r] = pp.blend_b[mbase1 + r]; }
        float lsum = 0.f;
        #pragma unroll
        for (int j = 0; j < 4; j++){
            int rown = n0 + j*16 + l16;
            f32x4 st0, st1;
            #pragma unroll
            for (int r = 0; r < 4; r++){
                float g0 = 1.f/(1.f + __expf(-(acc[j][r] + bias0[r])));
                float g1 = 1.f/(1.f + __expf(-(acc[4+j][r] + bias1[r])));
                lsum += g0 + g1;
                st0[r] = g0; st1[r] = g1;
            }
            *(f32x4*)(pp.gatebuf + (size_t)rown*D + mbase0) = st0;
            *(f32x4*)(pp.gatebuf + (size_t)rown*D + mbase1) = st1;
        }
        float* redp = &ep[0][0][0][0];
        redp[tid] = lsum;
        __syncthreads();
        for (int sft = 128; sft; sft >>= 1){
            if (tid < sft) redp[tid] += redp[tid + sft];
            __syncthreads();
        }
        if (tid == 0) atomicAdd(pp.sumBuf, redp[0]);
        return;
    }

    // ---- expert slice: head pair p -> heads 2p, 2p+1 ----
    int p = blockIdx.x;
    int m0 = p*128;
    const unsigned short* arow0 = pp.w1nk + (size_t)e*HHD*D + (size_t)(m0 + wave*16 + l16)*D + quad*8;
    const unsigned short* arow1 = arow0 + (size_t)64*D;
    const unsigned short* brow[4];
    bool zr[4];
    #pragma unroll
    for (int j = 0; j < 4; j++){
        int n = n0 + j*16 + l16;
        brow[j] = pp.featbf + (size_t)n*D + quad*8;
        zr[j] = (e > 0) ? (pp.rmask[(size_t)(e-1)*ROWS + n] == 0.f) : false;
    }
    f32x4 acc[8] = {z4, z4, z4, z4, z4, z4, z4, z4};
    bf8_t a0F = *(const bf8_t*)(arow0);
    bf8_t a1F = *(const bf8_t*)(arow1);
    bf8_t bF[4];
    #pragma unroll
    for (int j = 0; j < 4; j++) bF[j] = zr[j] ? bz : *(const bf8_t*)(brow[j]);
    #pragma unroll
    for (int it = 0; it < D/32; it++){
        bf8_t a0C = a0F, a1C = a1F;
        bf8_t bC[4] = {bF[0], bF[1], bF[2], bF[3]};
        if (it + 1 < D/32){
            int kn = (it + 1)*32;
            a0F = *(const bf8_t*)(arow0 + kn);
            a1F = *(const bf8_t*)(arow1 + kn);
            #pragma unroll
            for (int j = 0; j < 4; j++) bF[j] = zr[j] ? bz : *(const bf8_t*)(brow[j] + kn);
        }
        #pragma unroll
        for (int j = 0; j < 4; j++){
            acc[j]   = __builtin_amdgcn_mfma_f32_16x16x32_bf16(a0C, bC[j], acc[j],   0, 0, 0);
            acc[4+j] = __builtin_amdgcn_mfma_f32_16x16x32_bf16(a1C, bC[j], acc[4+j], 0, 0, 0);
        }
    }
    int b = n0 >> 10;
    int mbase0 = m0 + wave*16 + quad*4;
    int mbase1 = mbase0 + 64;
    int obase = wave*16 + quad*4;   // o within head (0..63)
    int h0 = p*2, h1 = p*2 + 1;
    // packed padded store: u32 (head2p | head2p+1<<16) at [row][o][p] with row stride 256 u32
    unsigned int* hp4 = (unsigned int*)pp.htn4;
    #pragma unroll
    for (int j = 0; j < 4; j++){
        int row = n0 + j*16 + l16;
        unsigned int* dst = hp4 + ((size_t)e*ROWS + row)*256 + obase*4 + p;
        dst[0]  = pk2(acc[j][0], acc[4+j][0]);
        dst[4]  = pk2(acc[j][1], acc[4+j][1]);
        dst[8]  = pk2(acc[j][2], acc[4+j][2]);
        dst[12] = pk2(acc[j][3], acc[4+j][3]);
    }
    const float* a1sp = (e == 0) ? pp.main_a1s : pp.dep_a1s + (size_t)(e-1)*H*HD;
    const float* a1dp = (e == 0) ? pp.main_a1d : pp.dep_a1d + (size_t)(e-1)*H*HD;
    float s0v[4], d0v[4], s1v[4], d1v[4];
    #pragma unroll
    for (int r = 0; r < 4; r++){
        s0v[r] = a1sp[mbase0 + r]; d0v[r] = a1dp[mbase0 + r];
        s1v[r] = a1sp[mbase1 + r]; d1v[r] = a1dp[mbase1 + r];
    }
    #pragma unroll
    for (int j = 0; j < 4; j++){
        float ps0 = 0.f, pd0 = 0.f, ps1 = 0.f, pd1 = 0.f;
        #pragma unroll
        for (int r = 0; r < 4; r++){
            ps0 += acc[j][r]*s0v[r];   pd0 += acc[j][r]*d0v[r];
            ps1 += acc[4+j][r]*s1v[r]; pd1 += acc[4+j][r]*d1v[r];
        }
        ep[0][0][j*16 + l16][wave*4 + quad] = ps0;
        ep[0][1][j*16 + l16][wave*4 + quad] = pd0;
        ep[1][0][j*16 + l16][wave*4 + quad] = ps1;
        ep[1][1][j*16 + l16][wave*4 + quad] = pd1;
    }
    float* mvb = pp.meanV1p + ((size_t)e*B + b)*512;
    #pragma unroll
    for (int r = 0; r < 4; r++){
        float cm0 = acc[0][r] + acc[1][r] + acc[2][r] + acc[3][r];
        float cm1 = acc[4][r] + acc[5][r] + acc[6][r] + acc[7][r];
        for (int off = 8; off; off >>= 1){
            cm0 += __shfl_down(cm0, off, 16);
            cm1 += __shfl_down(cm1, off, 16);
        }
        if (l16 == 0){
            atomicAdd(mvb + (obase + r)*8 + h0, cm0*(1.f/(float)S));
            atomicAdd(mvb + (obase + r)*8 + h1, cm1*(1.f/(float)S));
        }
    }
    __syncthreads();
    {
        int hh = tid >> 7, arr = (tid >> 6) & 1, sl = tid & 63;
        float sum = 0.f;
        #pragma unroll
        for (int i = 0; i < 16; i++) sum += ep[hh][arr][sl][i];
        int n = n0 + sl;
        float* dst = arr ? pp.ed8 : pp.es8;
        dst[(((size_t)e*B + (n >> 10))*S + (n & 1023))*8 + (p*2 + hh)] = sum;
    }
}

// ---------- attn1 gather v3: ONE block per (b,s), all 4 experts merged ----------
// waves 0,1: main weights; waves 2,3: deputy weights (tag by range).
// Gather: range-by-range; main V + deputy V per neighbor (uint4 loads, padded layout).
// grid (S, B), 256 threads
__global__ __launch_bounds__(256) void a1_kernel(P pp)
{
    __shared__ f32x4 wMa[MAXN], wMb[MAXN], wDa[MAXN], wDb[MAXN];  // 8 KB
    __shared__ f32x4 paccA[4][64], paccB[4][64];                  // 8 KB
    __shared__ float pdenM[2][6];
    __shared__ float pdenD[2][3][6];
    int tid = threadIdx.x, wave = tid >> 6, lane = tid & 63;
    int s = blockIdx.x, b = blockIdx.y;
    int row = b*S + s;
    int4 c = pp.nbc[row];
    const short* nl = pp.nbr + (size_t)row*MAXN;

    if (wave < 2){
        // main expert weights, i in [wave*64, wave*64+64)
        const float* esp = pp.es8 + ((size_t)b*S + s)*8;
        f32x4 eslo = *(const f32x4*)esp;
        f32x4 eshi = *(const f32x4*)(esp + 4);
        float esv[6] = {eslo[0], eslo[1], eslo[2], eslo[3], eshi[0], eshi[1]};
        const float* edb = pp.ed8 + (size_t)b*S*8;
        int i = wave*64 + lane;
        float w[6] = {0,0,0,0,0,0};
        if (i < c.x){
            int t = nl[i];
            const float* epn = edb + (size_t)t*8;
            f32x4 d0 = *(const f32x4*)epn;
            f32x4 d1 = *(const f32x4*)(epn + 4);
            float edv[6] = {d0[0], d0[1], d0[2], d0[3], d1[0], d1[1]};
            #pragma unroll
            for (int h = 0; h < 6; h++) w[h] = __expf(leaky(esv[h] + edv[h]));
            f32x4 ra = {w[0], w[1], w[2], w[3]};
            f32x4 rb = {w[4], w[5], i2f(t), 0.f};
            wMa[i] = ra; wMb[i] = rb;
        }
        #pragma unroll
        for (int h = 0; h < 6; h++){
            float x = w[h];
            for (int o2 = 32; o2; o2 >>= 1) x += __shfl_down(x, o2);
            if (lane == 0) pdenM[wave][h] = x;
        }
    } else {
        // deputy weights: expert = tag(i) from range partition
        int i = (wave - 2)*64 + lane;
        int tg = (i < c.y) ? 1 : ((i < c.z) ? 2 : 3);
        float w[6] = {0,0,0,0,0,0};
        if (i < c.x){
            int t = nl[i];
            const float* esp = pp.es8 + (((size_t)tg*B + b)*S + s)*8;
            f32x4 eslo = *(const f32x4*)esp;
            f32x4 eshi = *(const f32x4*)(esp + 4);
            const float* epn = pp.ed8 + (((size_t)tg*B + b)*S + (size_t)t)*8;
            f32x4 d0 = *(const f32x4*)epn;
            f32x4 d1 = *(const f32x4*)(epn + 4);
            float es6[6] = {eslo[0], eslo[1], eslo[2], eslo[3], eshi[0], eshi[1]};
            float ed6[6] = {d0[0], d0[1], d0[2], d0[3], d1[0], d1[1]};
            #pragma unroll
            for (int h = 0; h < 6; h++) w[h] = __expf(leaky(es6[h] + ed6[h]));
            // rmask-inactive neighbor rows have exactly-zero V: flag to skip gather (den still counts w)
            float zf = (pp.rmask[(size_t)(tg-1)*ROWS + (size_t)b*S + t] == 0.f) ? 1.f : 0.f;
            f32x4 ra = {w[0], w[1], w[2], w[3]};
            f32x4 rb = {w[4], w[5], zf, 0.f};
            wDa[i] = ra; wDb[i] = rb;
        }
        // per-tag masked reduces (w==0 for i>=c.x)
        #pragma unroll
        for (int g = 1; g <= 3; g++){
            #pragma unroll
            for (int h = 0; h < 6; h++){
                float x = (tg == g) ? w[h] : 0.f;
                for (int o2 = 32; o2; o2 >>= 1) x += __shfl_down(x, o2);
                if (lane == 0) pdenD[wave-2][g-1][h] = x;
            }
        }
    }
    __syncthreads();

    const unsigned int* V0 = (const unsigned int*)pp.htn4 + (size_t)b*S*256;
    float accM[6] = {0,0,0,0,0,0};
    int rlo[3] = {0, c.y, c.z};
    int rhi[3] = {c.y, c.z, c.x};
    for (int rg = 0; rg < 3; rg++){
        const unsigned int* Ve = (const unsigned int*)pp.htn4 + ((size_t)(rg+1)*ROWS + (size_t)b*S)*256;
        float accD[6] = {0,0,0,0,0,0};
        #pragma unroll 2
        for (int j = rlo[rg] + wave; j < rhi[rg]; j += 4){
            f32x4 ma = wMa[j], mb = wMb[j];
            f32x4 da = wDa[j], db = wDb[j];
            int t = f2i(mb[2]);
            uint4 vm = *(const uint4*)(V0 + ((size_t)t*64 + lane)*4);
            accM[0] += ma[0]*blo(vm.x); accM[1] += ma[1]*bhi(vm.x);
            accM[2] += ma[2]*blo(vm.y); accM[3] += ma[3]*bhi(vm.y);
            accM[4] += mb[0]*blo(vm.z); accM[5] += mb[1]*bhi(vm.z);
            if (db[2] == 0.f){
                uint4 vd = *(const uint4*)(Ve + ((size_t)t*64 + lane)*4);
                accD[0] += da[0]*blo(vd.x); accD[1] += da[1]*bhi(vd.x);
                accD[2] += da[2]*blo(vd.y); accD[3] += da[3]*bhi(vd.y);
                accD[4] += db[0]*blo(vd.z); accD[5] += db[1]*bhi(vd.z);
            }
        }
        // flush deputy rg+1
        {
            f32x4 pa = {accD[0], accD[1], accD[2], accD[3]};
            f32x4 pb = {accD[4], accD[5], 0.f, 0.f};
            paccA[wave][lane] = pa; paccB[wave][lane] = pb;
        }
        __syncthreads();
        if (wave == 0){
            unsigned short* outp = pp.h1c4 + ((size_t)(rg+1)*ROWS + row)*HHD;
            bool has = rhi[rg] > rlo[rg];
            const float* mv = pp.meanV1p + ((size_t)(rg+1)*B + b)*512 + lane*8;
            f32x4 q0 = paccA[0][lane], q1 = paccA[1][lane], q2 = paccA[2][lane], q3 = paccA[3][lane];
            f32x4 r0 = paccB[0][lane], r1 = paccB[1][lane], r2 = paccB[2][lane], r3 = paccB[3][lane];
            float sum6[6];
            sum6[0] = q0[0]+q1[0]+q2[0]+q3[0];
            sum6[1] = q0[1]+q1[1]+q2[1]+q3[1];
            sum6[2] = q0[2]+q1[2]+q2[2]+q3[2];
            sum6[3] = q0[3]+q1[3]+q2[3]+q3[3];
            sum6[4] = r0[0]+r1[0]+r2[0]+r3[0];
            sum6[5] = r0[1]+r1[1]+r2[1]+r3[1];
            #pragma unroll
            for (int h = 0; h < 6; h++){
                float den = pdenD[0][rg][h] + pdenD[1][rg][h];
                float v = has ? sum6[h]/den : mv[h];
                v = v > 0.f ? v : __expf(v) - 1.f;   // ELU
                outp[h*64 + lane] = f2bf(v);
            }
        }
        __syncthreads();
    }
    // flush main (c.x >= 1 always: self-loop)
    {
        f32x4 pa = {accM[0], accM[1], accM[2], accM[3]};
        f32x4 pb = {accM[4], accM[5], 0.f, 0.f};
        paccA[wave][lane] = pa; paccB[wave][lane] = pb;
    }
    __syncthreads();
    if (wave == 0){
        unsigned short* outp = pp.h1c4 + (size_t)row*HHD;
        f32x4 q0 = paccA[0][lane], q1 = paccA[1][lane], q2 = paccA[2][lane], q3 = paccA[3][lane];
        f32x4 r0 = paccB[0][lane], r1 = paccB[1][lane], r2 = paccB[2][lane], r3 = paccB[3][lane];
        float sum6[6];
        sum6[0] = q0[0]+q1[0]+q2[0]+q3[0];
        sum6[1] = q0[1]+q1[1]+q2[1]+q3[1];
        sum6[2] = q0[2]+q1[2]+q2[2]+q3[2];
        sum6[3] = q0[3]+q1[3]+q2[3]+q3[3];
        sum6[4] = r0[0]+r1[0]+r2[0]+r3[0];
        sum6[5] = r0[1]+r1[1]+r2[1]+r3[1];
        #pragma unroll
        for (int h = 0; h < 6; h++){
            float den = pdenM[0][h] + pdenM[1][h];
            float v = sum6[h]/den;
            v = v > 0.f ? v : __expf(v) - 1.f;   // ELU
            outp[h*64 + lane] = f2bf(v);
        }
    }
}

// ---------- GEMM2 (h1@W2) + fused f2s/f2d + colmean ----------
// grid (D/128=2, ROWS/64, 4)
__global__ __launch_bounds__(256, 4) void gemm2_kernel(P pp)
{
    __shared__ float ep[2][2][64][17];
    int tid = threadIdx.x, wave = tid >> 6, lane = tid & 63;
    int quad = lane >> 4, l16 = lane & 15;
    int e = blockIdx.z;
    int m0 = blockIdx.x*128;
    int n0 = blockIdx.y*64;
    f32x4 z4 = {0.f,0.f,0.f,0.f};
    const unsigned short* arow0 = pp.w2nk + (size_t)e*D*HHD + (size_t)(m0 + wave*16 + l16)*HHD + quad*8;
    const unsigned short* arow1 = arow0 + (size_t)64*HHD;
    const unsigned short* brow[4];
    #pragma unroll
    for (int j = 0; j < 4; j++)
        brow[j] = pp.h1c4 + (size_t)e*ROWS*HHD + (size_t)(n0 + j*16 + l16)*HHD + quad*8;
    f32x4 acc[8] = {z4, z4, z4, z4, z4, z4, z4, z4};
    bf8_t a0F = *(const bf8_t*)(arow0);
    bf8_t a1F = *(const bf8_t*)(arow1);
    bf8_t bF[4];
    #pragma unroll
    for (int j = 0; j < 4; j++) bF[j] = *(const bf8_t*)(brow[j]);
    #pragma unroll
    for (int it = 0; it < HHD/32; it++){
        bf8_t a0C = a0F, a1C = a1F;
        bf8_t bC[4] = {bF[0], bF[1], bF[2], bF[3]};
        if (it + 1 < HHD/32){
            int kn = (it + 1)*32;
            a0F = *(const bf8_t*)(arow0 + kn);
            a1F = *(const bf8_t*)(arow1 + kn);
            #pragma unroll
            for (int j = 0; j < 4; j++) bF[j] = *(const bf8_t*)(brow[j] + kn);
        }
        #pragma unroll
        for (int j = 0; j < 4; j++){
            acc[j]   = __builtin_amdgcn_mfma_f32_16x16x32_bf16(a0C, bC[j], acc[j],   0, 0, 0);
            acc[4+j] = __builtin_amdgcn_mfma_f32_16x16x32_bf16(a1C, bC[j], acc[4+j], 0, 0, 0);
        }
    }
    int b = n0 >> 10;
    int mbase0 = m0 + wave*16 + quad*4;
    int mbase1 = mbase0 + 64;
    #pragma unroll
    for (int j = 0; j < 4; j++){
        int row = n0 + j*16 + l16;
        ushort4 o0, o1;
        o0.x = f2bf(acc[j][0]);   o0.y = f2bf(acc[j][1]);
        o0.z = f2bf(acc[j][2]);   o0.w = f2bf(acc[j][3]);
        o1.x = f2bf(acc[4+j][0]); o1.y = f2bf(acc[4+j][1]);
        o1.z = f2bf(acc[4+j][2]); o1.w = f2bf(acc[4+j][3]);
        *(ushort4*)(pp.h2n4 + ((size_t)e*ROWS + row)*D + mbase0) = o0;
        *(ushort4*)(pp.h2n4 + ((size_t)e*ROWS + row)*D + mbase1) = o1;
    }
    const float* a2sp = (e == 0) ? pp.main_a2s : pp.dep_a2s + (size_t)(e-1)*D;
    const float* a2dp = (e == 0) ? pp.main_a2d : pp.dep_a2d + (size_t)(e-1)*D;
    float s0v[4], d0v[4], s1v[4], d1v[4];
    #pragma unroll
    for (int r = 0; r < 4; r++){
        s0v[r] = a2sp[mbase0 + r]; d0v[r] = a2dp[mbase0 + r];
        s1v[r] = a2sp[mbase1 + r]; d1v[r] = a2dp[mbase1 + r];
    }
    #pragma unroll
    for (int j = 0; j < 4; j++){
        float ps0 = 0.f, pd0 = 0.f, ps1 = 0.f, pd1 = 0.f;
        #pragma unroll
        for (int r = 0; r < 4; r++){
            ps0 += acc[j][r]*s0v[r];   pd0 += acc[j][r]*d0v[r];
            ps1 += acc[4+j][r]*s1v[r]; pd1 += acc[4+j][r]*d1v[r];
        }
        ep[0][0][j*16 + l16][wave*4 + quad] = ps0;
        ep[0][1][j*16 + l16][wave*4 + quad] = pd0;
        ep[1][0][j*16 + l16][wave*4 + quad] = ps1;
        ep[1][1][j*16 + l16][wave*4 + quad] = pd1;
    }
    #pragma unroll
    for (int r = 0; r < 4; r++){
        float cm0 = acc[0][r] + acc[1][r] + acc[2][r] + acc[3][r];
        float cm1 = acc[4][r] + acc[5][r] + acc[6][r] + acc[7][r];
        for (int off = 8; off; off >>= 1){
            cm0 += __shfl_down(cm0, off, 16);
            cm1 += __shfl_down(cm1, off, 16);
        }
        if (l16 == 0){
            atomicAdd(pp.meanV2 + ((size_t)e*B + b)*D + mbase0 + r, cm0*(1.f/(float)S));
            atomicAdd(pp.meanV2 + ((size_t)e*B + b)*D + mbase1 + r, cm1*(1.f/(float)S));
        }
    }
    __syncthreads();
    {
        int hh = tid >> 7, arr = (tid >> 6) & 1, sl = tid & 63;
        float sum = 0.f;
        #pragma unroll
        for (int i = 0; i < 16; i++) sum += ep[hh][arr][sl][i];
        int n = n0 + sl;
        float* dst = arr ? pp.f2d4 : pp.f2s4;
        atomicAdd(dst + (size_t)e*ROWS + n, sum);
    }
}

// ---------- attn2 + blend: waves 0,1 main; waves 2,3 active deputies ----------
// grid (S, B), 256 threads
__global__ __launch_bounds__(256) void a2_kernel(P pp)
{
    __shared__ float2 wrec0[MAXN];
    __shared__ float2 wrec1[MAXN];
    __shared__ float pacc[3][256];
    __shared__ float pden[4][4];
    int tid = threadIdx.x;
    int wave = tid >> 6, lane = tid & 63;
    int s = blockIdx.x, b = blockIdx.y;
    int row = b*S + s;
    int4 c = pp.nbc[row];
    float rm0 = pp.rmask[row], rm1 = pp.rmask[ROWS + row], rm2 = pp.rmask[2*ROWS + row];
    const short* nl = pp.nbr + (size_t)row*MAXN;
    // ---- weight phase ----
    if (wave < 2){
        int i = wave*64 + lane;
        float w = 0.f;
        if (i < c.x){
            int t = nl[i];
            float fs = pp.f2s4[row];
            w = __expf(leaky(fs + pp.f2d4[(size_t)b*S + t]));
            float2 r; r.x = w; r.y = i2f(t);
            wrec0[i] = r;
        }
        float dsum = w;
        for (int o2 = 32; o2; o2 >>= 1) dsum += __shfl_down(dsum, o2);
        if (lane == 0) pden[wave][0] = dsum;
    } else {
        int i = (wave - 2)*64 + lane;
        float w = 0.f, d1 = 0.f, d2 = 0.f, d3 = 0.f;
        if (i < c.x){
            int t = nl[i];
            int tag = (i < c.y) ? 1 : ((i < c.z) ? 2 : 3);
            float act = (tag == 1) ? rm0 : ((tag == 2) ? rm1 : rm2);
            if (act != 0.f){
                float fs = pp.f2s4[(size_t)tag*ROWS + row];
                w = __expf(leaky(fs + pp.f2d4[(size_t)tag*ROWS + (size_t)b*S + t]));
            }
            float2 r; r.x = w; r.y = i2f(t);
            wrec1[i] = r;
            if (tag == 1) d1 = w; else if (tag == 2) d2 = w; else d3 = w;
        }
        for (int o2 = 32; o2; o2 >>= 1){
            d1 += __shfl_down(d1, o2);
            d2 += __shfl_down(d2, o2);
            d3 += __shfl_down(d3, o2);
        }
        if (lane == 0){ pden[wave][1] = d1; pden[wave][2] = d2; pden[wave][3] = d3; }
    }
    __syncthreads();
    // ---- gather phase ----
    float acc[4] = {0.f, 0.f, 0.f, 0.f};
    if (wave < 2){
        float inv = 1.f/(pden[0][0] + pden[1][0]);   // c.x >= 1 (self-loop) always
        const unsigned short* V = pp.h2n4 + (size_t)b*S*D;
        #pragma unroll 4
        for (int j = wave; j < c.x; j += 2){
            float2 r = wrec0[j];
            float wv = r.x*inv;
            int t = f2i(r.y);
            const unsigned short* vp = V + (size_t)t*D + lane*4;
            uint2 dv = *(const uint2*)vp;
            acc[0] += wv*blo(dv.x); acc[1] += wv*bhi(dv.x);
            acc[2] += wv*blo(dv.y); acc[3] += wv*bhi(dv.y);
        }
    } else {
        int rlo[3] = {0, c.y, c.z};
        int rhi[3] = {c.y, c.z, c.x};
        float ract[3] = {rm0, rm1, rm2};
        for (int rg = 0; rg < 3; rg++){
            if (ract[rg] == 0.f || rhi[rg] <= rlo[rg]) continue;
            float inv = 1.f/(pden[2][rg+1] + pden[3][rg+1]);
            const unsigned short* V = pp.h2n4 + ((size_t)(rg+1)*ROWS + (size_t)b*S)*D;
            #pragma unroll 4
            for (int j = rlo[rg] + (wave - 2); j < rhi[rg]; j += 2){
                float2 r = wrec1[j];
                float wv = r.x*inv;
                int t = f2i(r.y);
                const unsigned short* vp = V + (size_t)t*D + lane*4;
                uint2 dv = *(const uint2*)vp;
                acc[0] += wv*blo(dv.x); acc[1] += wv*bhi(dv.x);
                acc[2] += wv*blo(dv.y); acc[3] += wv*bhi(dv.y);
            }
        }
    }
    if (wave >= 1){
        #pragma unroll
        for (int q = 0; q < 4; q++) pacc[wave-1][lane*4 + q] = acc[q];
    }
    __syncthreads();
    // ---- combine + blend (wave 0) ----
    if (wave == 0){
        float4 g4 = *(const float4*)(pp.gatebuf + (size_t)row*D + lane*4);
        float dep_mv[4] = {0.f, 0.f, 0.f, 0.f};
        if (rm0 != 0.f && c.y == 0){
            float4 mv = *(const float4*)(pp.meanV2 + ((size_t)1*B + b)*D + lane*4);
            dep_mv[0] += mv.x; dep_mv[1] += mv.y; dep_mv[2] += mv.z; dep_mv[3] += mv.w;
        }
        if (rm1 != 0.f && c.z == c.y){
            float4 mv = *(const float4*)(pp.meanV2 + ((size_t)2*B + b)*D + lane*4);
            dep_mv[0] += mv.x; dep_mv[1] += mv.y; dep_mv[2] += mv.z; dep_mv[3] += mv.w;
        }
        if (rm2 != 0.f && c.x == c.z){
            float4 mv = *(const float4*)(pp.meanV2 + ((size_t)3*B + b)*D + lane*4);
            dep_mv[0] += mv.x; dep_mv[1] += mv.y; dep_mv[2] += mv.z; dep_mv[3] += mv.w;
        }
        float g[4] = {g4.x, g4.y, g4.z, g4.w};
        float4 o;
        float* op = &o.x;
        #pragma unroll
        for (int q = 0; q < 4; q++){
            int col = lane*4 + q;
            float a0 = acc[q] + pacc[0][col];
            float dep = pacc[1][col] + pacc[2][col] + dep_mv[q];
            op[q] = g[q]*a0 + (1.f - g[q])*dep;
        }
        *(float4*)(pp.outp + (size_t)row*D + lane*4) = o;
    }
    if (blockIdx.x == 0 && blockIdx.y == 0 && tid == 0){
        float mc = pp.sumBuf[0] / (float)(ROWS*D);
        pp.outp[ROWS*D]     = fabsf(mc - 0.6f)*0.01f;
        pp.outp[ROWS*D + 1] = mc;
    }
}

extern "C" void kernel_launch(void* const* d_in, const int* in_sizes, int n_in,
                              void* d_out, int out_size, void* d_ws, size_t ws_size,
                              hipStream_t stream)
{
    P hp;
    hp.feature  = (const float*)d_in[0];
    hp.adj      = (const float*)d_in[1];
    hp.main_W1  = (const float*)d_in[2];
    hp.main_a1s = (const float*)d_in[3];
    hp.main_a1d = (const float*)d_in[4];
    hp.main_W2  = (const float*)d_in[5];
    hp.main_a2s = (const float*)d_in[6];
    hp.main_a2d = (const float*)d_in[7];
    hp.dep_W1   = (const float*)d_in[8];
    hp.dep_a1s  = (const float*)d_in[9];
    hp.dep_a1d  = (const float*)d_in[10];
    hp.dep_W2   = (const float*)d_in[11];
    hp.dep_a2s  = (const float*)d_in[12];
    hp.dep_a2d  = (const float*)d_in[13];
    hp.router_W = (const float*)d_in[14];
    hp.blend_W  = (const float*)d_in[15];
    hp.blend_b  = (const float*)d_in[16];
    hp.doc_p    = (const int*)d_in[17];
    hp.sect_p   = (const int*)d_in[18];

    char* ws = (char*)d_ws;
    size_t off = 0;
    hp.featbf = (unsigned short*)(ws + off); off += (size_t)ROWS*D*2;        // 2 MB
    hp.nbr    = (short*)(ws + off);          off += (size_t)ROWS*MAXN*2;     // 1 MB
    hp.nbc    = (int4*)(ws + off);           off += (size_t)ROWS*16;         // 64 KB
    hp.w1nk   = (unsigned short*)(ws + off); off += (size_t)4*HHD*D*2;
    hp.w2nk   = (unsigned short*)(ws + off); off += (size_t)4*D*HHD*2;
    hp.bwt    = (unsigned short*)(ws + off); off += (size_t)D*D*2;
    hp.es8 = (float*)(ws + off); off += (size_t)4*B*S*8*4;   // 512 KB
    hp.ed8 = (float*)(ws + off); off += (size_t)4*B*S*8*4;   // 512 KB
    hp.gatebuf = (float*)(ws + off); off += (size_t)ROWS*D*4;                // 4 MB
    hp.htn4 = (unsigned short*)(ws + off); off += (size_t)4*ROWS*256*4;      // 16 MB (padded [row][o][4] u32 layout)
    hp.h2n4 = (unsigned short*)(ws + off); off += (size_t)4*ROWS*D*2;        // 8 MB
    hp.h1c4 = (unsigned short*)(ws + off); off += (size_t)4*ROWS*HHD*2;      // 12 MB
    // contiguous zero region (NZERO floats) starts at f2s4:
    hp.f2s4    = (float*)(ws + off); off += (size_t)4*ROWS*4;
    hp.f2d4    = (float*)(ws + off); off += (size_t)4*ROWS*4;
    hp.meanV1p = (float*)(ws + off); off += (size_t)4*B*512*4;
    hp.meanV2  = (float*)(ws + off); off += (size_t)4*B*D*4;
    hp.sumBuf  = (float*)(ws + off); off += 128;
    hp.rmask   = (float*)(ws + off); off += (size_t)NE*ROWS*4;
    hp.outp    = (float*)d_out;

    prep_kernel<<<PB_TOTAL, 256, 0, stream>>>(hp);
    gemm1_kernel<<<dim3(3, ROWS/64, 5), 256, 0, stream>>>(hp);
    a1_kernel<<<dim3(S, B), 256, 0, stream>>>(hp);
    gemm2_kernel<<<dim3(D/128, ROWS/64, 4), 256, 0, stream>>>(hp);
    a2_kernel<<<dim3(S, B), 256, 0, stream>>>(hp);
}

// Round 5
// 221.510 us; speedup vs baseline: 3.7053x; 1.0202x over previous
//
#include <hip/hip_runtime.h>
#include <math.h>

#define B 4
#define S 1024
#define D 256
#define H 6
#define HD 64
#define NE 3
#define HHD 384
#define ROWS (B*S)
#define MAXN 128
#define PLN ((size_t)ROWS*64)   // u32 elements per (e,p) plane

typedef __attribute__((ext_vector_type(8))) short bf8_t;
typedef __attribute__((ext_vector_type(4))) float f32x4;

__device__ __forceinline__ float leaky(float x){ return x > 0.f ? x : 0.2f*x; }

__device__ __forceinline__ unsigned short f2bf(float f){
    union { float f; unsigned int u; } v; v.f = f;
    unsigned int u = v.u;
    return (unsigned short)((u + 0x7FFFu + ((u >> 16) & 1u)) >> 16);
}
__device__ __forceinline__ float bf2f(unsigned short h){
    union { unsigned int u; float f; } v; v.u = ((unsigned int)h) << 16;
    return v.f;
}
__device__ __forceinline__ float blo(unsigned int u){
    union { unsigned int u; float f; } v; v.u = u << 16; return v.f;
}
__device__ __forceinline__ float bhi(unsigned int u){
    union { unsigned int u; float f; } v; v.u = u & 0xffff0000u; return v.f;
}
__device__ __forceinline__ float i2f(int t){
    union { int i; float f; } v; v.i = t; return v.f;
}
__device__ __forceinline__ int f2i(float f){
    union { float f; int i; } v; v.f = f; return v.i;
}
__device__ __forceinline__ unsigned int pk2(float lo, float hi){
    return (unsigned)f2bf(lo) | ((unsigned)f2bf(hi) << 16);
}

// ---------- params ----------
struct P {
    const float *feature, *adj;
    const float *main_W1, *dep_W1, *main_W2, *dep_W2, *blend_W, *router_W;
    const int *doc_p, *sect_p;
    const float *main_a1s, *main_a1d, *dep_a1s, *dep_a1d;
    const float *main_a2s, *main_a2d, *dep_a2s, *dep_a2d;
    const float *blend_b;
    unsigned short *featbf; short *nbr; int4 *nbc;
    unsigned short *w1nk, *w2nk, *bwt;
    float *es8, *ed8, *gatebuf;
    unsigned int *htp;                 // compact planes [e][p][ROWS][64] u32 (pair-packed bf16)
    unsigned short *h2n4, *h1c4;
    float *f2s4, *f2d4, *meanV1p, *meanV2, *sumBuf, *rmask;
    float *outp;
};

// ---------- block ranges for prep ----------
#define PB_CONV   1024
#define PB_NBR    1024
#define PB_W1     1536
#define PB_W2     1536
#define PB_BW      256
#define PB_ZERO    177
#define PB_ROUTER 1024
#define PB_TOTAL  (PB_CONV + PB_NBR + PB_W1 + PB_W2 + PB_BW + PB_ZERO + PB_ROUTER)
#define NZERO     45088

__global__ __launch_bounds__(256) void prep_kernel(P pp)
{
    int blk = blockIdx.x, tid = threadIdx.x;
    if (blk < PB_CONV){
        int idx = blk*256 + tid;                       // < ROWS*D/4
        float4 v = ((const float4*)pp.feature)[idx];
        ushort4 o;
        o.x = f2bf(v.x); o.y = f2bf(v.y); o.z = f2bf(v.z); o.w = f2bf(v.w);
        ((ushort4*)pp.featbf)[idx] = o;
        return;
    }
    blk -= PB_CONV;
    if (blk < PB_NBR){
        int wave = tid >> 6, lane = tid & 63;
        int row = blk*4 + wave;
        int b1 = S - *pp.sect_p - *pp.doc_p;
        int b2 = S - *pp.doc_p;
        const float* ar = pp.adj + (size_t)row*S + lane*16;
        float a[16];
        #pragma unroll
        for (int q = 0; q < 4; q++){
            float4 v = ((const float4*)ar)[q];
            a[q*4+0] = v.x; a[q*4+1] = v.y; a[q*4+2] = v.z; a[q*4+3] = v.w;
        }
        int t0 = lane*16;
        int k = 0, c1 = 0, c2 = 0;
        #pragma unroll
        for (int i = 0; i < 16; i++){
            if (a[i] > 0.f){
                k++;
                int t = t0 + i;
                if (t < b1) c1++;
                if (t < b2) c2++;
            }
        }
        int inc = k;
        #pragma unroll
        for (int d = 1; d < 64; d <<= 1){
            int u = __shfl_up(inc, d);
            if (lane >= d) inc += u;
        }
        int off = inc - k;
        int total = __shfl(inc, 63);
        int o = row*MAXN + off;
        #pragma unroll
        for (int i = 0; i < 16; i++){
            if (a[i] > 0.f) pp.nbr[o++] = (short)(t0 + i);
        }
        for (int d = 32; d; d >>= 1){
            c1 += __shfl_down(c1, d);
            c2 += __shfl_down(c2, d);
        }
        if (lane == 0) pp.nbc[row] = make_int4(total, c1, c2, 0);
        return;
    }
    blk -= PB_NBR;
    if (blk < PB_W1){
        int e = blk / 384;
        int idx = (blk - e*384)*256 + tid;             // < HHD*D
        const float* src = (e == 0) ? pp.main_W1 : pp.dep_W1 + (size_t)(e-1)*H*D*HD;
        int n = idx >> 8, k = idx & 255;
        int h = n >> 6, o = n & 63;
        pp.w1nk[(size_t)e*HHD*D + idx] = f2bf(src[(h*D + k)*HD + o]);
        return;
    }
    blk -= PB_W1;
    if (blk < PB_W2){
        int g = blk*256 + tid;                         // < 4*D*HHD
        int e = g / (D*HHD);
        int rem = g - e*(D*HHD);
        int n = rem / HHD, k = rem - n*HHD;
        const float* src = (e == 0) ? pp.main_W2 : pp.dep_W2 + (size_t)(e-1)*HHD*D;
        pp.w2nk[g] = f2bf(src[k*D + n]);
        return;
    }
    blk -= PB_W2;
    if (blk < PB_BW){
        int col = blk, k = tid;
        pp.bwt[col*D + k] = f2bf(pp.blend_W[k*D + col]);
        return;
    }
    blk -= PB_BW;
    if (blk < PB_ZERO){
        int idx = blk*256 + tid;
        if (idx < NZERO) pp.f2s4[idx] = 0.f;           // contiguous zero region base
        return;
    }
    blk -= PB_ZERO;
    {
        int wave = tid >> 6, lane = tid & 63;
        int row = blk*4 + wave;
        float4 xv = ((const float4*)(pp.feature + (size_t)row*D))[lane];
        int f = lane*4;
        float xa[4] = {xv.x, xv.y, xv.z, xv.w};
        float p0 = 0.f, p1 = 0.f, p2 = 0.f;
        #pragma unroll
        for (int j = 0; j < 4; j++){
            p0 += xa[j]*pp.router_W[(f+j)*NE + 0];
            p1 += xa[j]*pp.router_W[(f+j)*NE + 1];
            p2 += xa[j]*pp.router_W[(f+j)*NE + 2];
        }
        for (int off = 32; off; off >>= 1){
            p0 += __shfl_down(p0, off);
            p1 += __shfl_down(p1, off);
            p2 += __shfl_down(p2, off);
        }
        if (lane == 0){
            float p[3] = {p0, p1, p2};
            int ex = 0;
            for (int e = 1; e < NE; e++) if (p[e] <= p[ex]) ex = e;
            for (int e = 0; e < NE; e++) pp.rmask[e*ROWS + row] = (e == ex) ? 0.f : 1.f;
        }
    }
}

// ---------- GEMM1 (x@W1) + fused es/ed + colmean ----------
// htp store via LDS transpose: compact planes [e][p][row][64] u32, coalesced uint4 bursts.
// grid (3, ROWS/64, 5). z<4: expert slices; z==4: blend gate (x<2).
__global__ __launch_bounds__(256, 4) void gemm1_kernel(P pp)
{
    __shared__ __align__(16) char smem[17408];
    float (*ep)[2][64][17] = (float (*)[2][64][17])smem;      // es/ed reduce buffer
    unsigned int (*tile)[68] = (unsigned int (*)[68])smem;     // [64][68] u32 = 17408 B
    int tid = threadIdx.x, wave = tid >> 6, lane = tid & 63;
    int quad = lane >> 4, l16 = lane & 15;
    int e = blockIdx.z;
    int n0 = blockIdx.y*64;
    f32x4 z4 = {0.f,0.f,0.f,0.f};
    bf8_t bz = {0,0,0,0,0,0,0,0};

    if (e == 4){
        // ---- blend gate GEMM ----
        if (blockIdx.x >= 2) return;
        int m0 = blockIdx.x*128;
        const unsigned short* arow0 = pp.bwt + (size_t)(m0 + wave*16 + l16)*D + quad*8;
        const unsigned short* arow1 = arow0 + (size_t)64*D;
        const unsigned short* brow[4];
        #pragma unroll
        for (int j = 0; j < 4; j++)
            brow[j] = pp.featbf + (size_t)(n0 + j*16 + l16)*D + quad*8;
        f32x4 acc[8] = {z4, z4, z4, z4, z4, z4, z4, z4};
        bf8_t a0F = *(const bf8_t*)(arow0);
        bf8_t a1F = *(const bf8_t*)(arow1);
        bf8_t bF[4];
        #pragma unroll
        for (int j = 0; j < 4; j++) bF[j] = *(const bf8_t*)(brow[j]);
        #pragma unroll
        for (int it = 0; it < D/32; it++){
            bf8_t a0C = a0F, a1C = a1F;
            bf8_t bC[4] = {bF[0], bF[1], bF[2], bF[3]};
            if (it + 1 < D/32){
                int kn = (it + 1)*32;
                a0F = *(const bf8_t*)(arow0 + kn);
                a1F = *(const bf8_t*)(arow1 + kn);
                #pragma unroll
                for (int j = 0; j < 4; j++) bF[j] = *(const bf8_t*)(brow[j] + kn);
            }
            #pragma unroll
            for (int j = 0; j < 4; j++){
                acc[j]   = __builtin_amdgcn_mfma_f32_16x16x32_bf16(a0C, bC[j], acc[j],   0, 0, 0);
                acc[4+j] = __builtin_amdgcn_mfma_f32_16x16x32_bf16(a1C, bC[j], acc[4+j], 0, 0, 0);
            }
        }
        int mbase0 = m0 + wave*16 + quad*4;
        int mbase1 = mbase0 + 64;
        float bias0[4], bias1[4];
        #pragma unroll
        for (int r = 0; r < 4; r++){ bias0[r] = pp.blend_b[mbase0 + r]; bias1[r] = pp.blend_b[mbase1 + r]; }
        float lsum = 0.f;
        #pragma unroll
        for (int j = 0; j < 4; j++){
            int rown = n0 + j*16 + l16;
            f32x4 st0, st1;
            #pragma unroll
            for (int r = 0; r < 4; r++){
                float g0 = 1.f/(1.f + __expf(-(acc[j][r] + bias0[r])));
                float g1 = 1.f/(1.f + __expf(-(acc[4+j][r] + bias1[r])));
                lsum += g0 + g1;
                st0[r] = g0; st1[r] = g1;
            }
            *(f32x4*)(pp.gatebuf + (size_t)rown*D + mbase0) = st0;
            *(f32x4*)(pp.gatebuf + (size_t)rown*D + mbase1) = st1;
        }
        float* redp = (float*)smem;
        redp[tid] = lsum;
        __syncthreads();
        for (int sft = 128; sft; sft >>= 1){
            if (tid < sft) redp[tid] += redp[tid + sft];
            __syncthreads();
        }
        if (tid == 0) atomicAdd(pp.sumBuf, redp[0]);
        return;
    }

    // ---- expert slice: head pair p -> heads 2p, 2p+1 ----
    int p = blockIdx.x;
    int m0 = p*128;
    const unsigned short* arow0 = pp.w1nk + (size_t)e*HHD*D + (size_t)(m0 + wave*16 + l16)*D + quad*8;
    const unsigned short* arow1 = arow0 + (size_t)64*D;
    const unsigned short* brow[4];
    bool zr[4];
    #pragma unroll
    for (int j = 0; j < 4; j++){
        int n = n0 + j*16 + l16;
        brow[j] = pp.featbf + (size_t)n*D + quad*8;
        zr[j] = (e > 0) ? (pp.rmask[(size_t)(e-1)*ROWS + n] == 0.f) : false;
    }
    f32x4 acc[8] = {z4, z4, z4, z4, z4, z4, z4, z4};
    bf8_t a0F = *(const bf8_t*)(arow0);
    bf8_t a1F = *(const bf8_t*)(arow1);
    bf8_t bF[4];
    #pragma unroll
    for (int j = 0; j < 4; j++) bF[j] = zr[j] ? bz : *(const bf8_t*)(brow[j]);
    #pragma unroll
    for (int it = 0; it < D/32; it++){
        bf8_t a0C = a0F, a1C = a1F;
        bf8_t bC[4] = {bF[0], bF[1], bF[2], bF[3]};
        if (it + 1 < D/32){
            int kn = (it + 1)*32;
            a0F = *(const bf8_t*)(arow0 + kn);
            a1F = *(const bf8_t*)(arow1 + kn);
            #pragma unroll
            for (int j = 0; j < 4; j++) bF[j] = zr[j] ? bz : *(const bf8_t*)(brow[j] + kn);
        }
        #pragma unroll
        for (int j = 0; j < 4; j++){
            acc[j]   = __builtin_amdgcn_mfma_f32_16x16x32_bf16(a0C, bC[j], acc[j],   0, 0, 0);
            acc[4+j] = __builtin_amdgcn_mfma_f32_16x16x32_bf16(a1C, bC[j], acc[4+j], 0, 0, 0);
        }
    }
    int b = n0 >> 10;
    int mbase0 = m0 + wave*16 + quad*4;
    int mbase1 = mbase0 + 64;
    int obase = wave*16 + quad*4;   // o within head (0..63)
    int h0 = p*2, h1 = p*2 + 1;
    // ---- es/ed epilogue (uses ep) ----
    const float* a1sp = (e == 0) ? pp.main_a1s : pp.dep_a1s + (size_t)(e-1)*H*HD;
    const float* a1dp = (e == 0) ? pp.main_a1d : pp.dep_a1d + (size_t)(e-1)*H*HD;
    float s0v[4], d0v[4], s1v[4], d1v[4];
    #pragma unroll
    for (int r = 0; r < 4; r++){
        s0v[r] = a1sp[mbase0 + r]; d0v[r] = a1dp[mbase0 + r];
        s1v[r] = a1sp[mbase1 + r]; d1v[r] = a1dp[mbase1 + r];
    }
    #pragma unroll
    for (int j = 0; j < 4; j++){
        float ps0 = 0.f, pd0 = 0.f, ps1 = 0.f, pd1 = 0.f;
        #pragma unroll
        for (int r = 0; r < 4; r++){
            ps0 += acc[j][r]*s0v[r];   pd0 += acc[j][r]*d0v[r];
            ps1 += acc[4+j][r]*s1v[r]; pd1 += acc[4+j][r]*d1v[r];
        }
        ep[0][0][j*16 + l16][wave*4 + quad] = ps0;
        ep[0][1][j*16 + l16][wave*4 + quad] = pd0;
        ep[1][0][j*16 + l16][wave*4 + quad] = ps1;
        ep[1][1][j*16 + l16][wave*4 + quad] = pd1;
    }
    float* mvb = pp.meanV1p + ((size_t)e*B + b)*512;
    #pragma unroll
    for (int r = 0; r < 4; r++){
        float cm0 = acc[0][r] + acc[1][r] + acc[2][r] + acc[3][r];
        float cm1 = acc[4][r] + acc[5][r] + acc[6][r] + acc[7][r];
        for (int off = 8; off; off >>= 1){
            cm0 += __shfl_down(cm0, off, 16);
            cm1 += __shfl_down(cm1, off, 16);
        }
        if (l16 == 0){
            atomicAdd(mvb + (obase + r)*8 + h0, cm0*(1.f/(float)S));
            atomicAdd(mvb + (obase + r)*8 + h1, cm1*(1.f/(float)S));
        }
    }
    __syncthreads();
    {
        int hh = tid >> 7, arr = (tid >> 6) & 1, sl = tid & 63;
        float sum = 0.f;
        #pragma unroll
        for (int i = 0; i < 16; i++) sum += ep[hh][arr][sl][i];
        int n = n0 + sl;
        float* dst = arr ? pp.ed8 : pp.es8;
        dst[(((size_t)e*B + (n >> 10))*S + (n & 1023))*8 + (p*2 + hh)] = sum;
    }
    __syncthreads();
    // ---- packed tile -> LDS (transpose), then coalesced uint4 store to compact plane ----
    #pragma unroll
    for (int j = 0; j < 4; j++){
        int rloc = j*16 + l16;
        tile[rloc][obase + 0] = pk2(acc[j][0], acc[4+j][0]);
        tile[rloc][obase + 1] = pk2(acc[j][1], acc[4+j][1]);
        tile[rloc][obase + 2] = pk2(acc[j][2], acc[4+j][2]);
        tile[rloc][obase + 3] = pk2(acc[j][3], acc[4+j][3]);
    }
    __syncthreads();
    {
        unsigned int* plane = pp.htp + (size_t)(e*3 + p)*PLN;
        int o4 = (tid & 15)*4;
        int rsub = tid >> 4;    // 0..15
        #pragma unroll
        for (int pass = 0; pass < 4; pass++){
            int rloc = pass*16 + rsub;
            uint4 v = *(const uint4*)&tile[rloc][o4];
            *(uint4*)(plane + (size_t)(n0 + rloc)*64 + o4) = v;
        }
    }
}

// ---------- attn1 gather v4: ONE block per (b,s); compact-plane dword loads ----------
// waves 0,1: main weights; waves 2,3: deputy weights (tag by range).
// grid (S, B), 256 threads
__global__ __launch_bounds__(256) void a1_kernel(P pp)
{
    __shared__ f32x4 wMa[MAXN], wMb[MAXN], wDa[MAXN], wDb[MAXN];  // 8 KB
    __shared__ f32x4 paccA[4][64], paccB[4][64];                  // 8 KB
    __shared__ float pdenM[2][6];
    __shared__ float pdenD[2][3][6];
    int tid = threadIdx.x, wave = tid >> 6, lane = tid & 63;
    int s = blockIdx.x, b = blockIdx.y;
    int row = b*S + s;
    int4 c = pp.nbc[row];
    const short* nl = pp.nbr + (size_t)row*MAXN;

    if (wave < 2){
        // main expert weights, i in [wave*64, wave*64+64)
        const float* esp = pp.es8 + ((size_t)b*S + s)*8;
        f32x4 eslo = *(const f32x4*)esp;
        f32x4 eshi = *(const f32x4*)(esp + 4);
        float esv[6] = {eslo[0], eslo[1], eslo[2], eslo[3], eshi[0], eshi[1]};
        const float* edb = pp.ed8 + (size_t)b*S*8;
        int i = wave*64 + lane;
        float w[6] = {0,0,0,0,0,0};
        if (i < c.x){
            int t = nl[i];
            const float* epn = edb + (size_t)t*8;
            f32x4 d0 = *(const f32x4*)epn;
            f32x4 d1 = *(const f32x4*)(epn + 4);
            float edv[6] = {d0[0], d0[1], d0[2], d0[3], d1[0], d1[1]};
            #pragma unroll
            for (int h = 0; h < 6; h++) w[h] = __expf(leaky(esv[h] + edv[h]));
            f32x4 ra = {w[0], w[1], w[2], w[3]};
            f32x4 rb = {w[4], w[5], i2f(t), 0.f};
            wMa[i] = ra; wMb[i] = rb;
        }
        #pragma unroll
        for (int h = 0; h < 6; h++){
            float x = w[h];
            for (int o2 = 32; o2; o2 >>= 1) x += __shfl_down(x, o2);
            if (lane == 0) pdenM[wave][h] = x;
        }
    } else {
        // deputy weights: expert = tag(i) from range partition
        int i = (wave - 2)*64 + lane;
        int tg = (i < c.y) ? 1 : ((i < c.z) ? 2 : 3);
        float w[6] = {0,0,0,0,0,0};
        if (i < c.x){
            int t = nl[i];
            const float* esp = pp.es8 + (((size_t)tg*B + b)*S + s)*8;
            f32x4 eslo = *(const f32x4*)esp;
            f32x4 eshi = *(const f32x4*)(esp + 4);
            const float* epn = pp.ed8 + (((size_t)tg*B + b)*S + (size_t)t)*8;
            f32x4 d0 = *(const f32x4*)epn;
            f32x4 d1 = *(const f32x4*)(epn + 4);
            float es6[6] = {eslo[0], eslo[1], eslo[2], eslo[3], eshi[0], eshi[1]};
            float ed6[6] = {d0[0], d0[1], d0[2], d0[3], d1[0], d1[1]};
            #pragma unroll
            for (int h = 0; h < 6; h++) w[h] = __expf(leaky(es6[h] + ed6[h]));
            // rmask-inactive neighbor rows have exactly-zero V: flag to skip gather (den still counts w)
            float zf = (pp.rmask[(size_t)(tg-1)*ROWS + (size_t)b*S + t] == 0.f) ? 1.f : 0.f;
            f32x4 ra = {w[0], w[1], w[2], w[3]};
            f32x4 rb = {w[4], w[5], zf, 0.f};
            wDa[i] = ra; wDb[i] = rb;
        }
        // per-tag masked reduces (w==0 for i>=c.x)
        #pragma unroll
        for (int g = 1; g <= 3; g++){
            #pragma unroll
            for (int h = 0; h < 6; h++){
                float x = (tg == g) ? w[h] : 0.f;
                for (int o2 = 32; o2; o2 >>= 1) x += __shfl_down(x, o2);
                if (lane == 0) pdenD[wave-2][g-1][h] = x;
            }
        }
    }
    __syncthreads();

    // plane bases for this batch, offset by lane (lane = o)
    const unsigned int* Vm = pp.htp + (size_t)b*S*64 + lane;
    float accM[6] = {0,0,0,0,0,0};
    int rlo[3] = {0, c.y, c.z};
    int rhi[3] = {c.y, c.z, c.x};
    for (int rg = 0; rg < 3; rg++){
        const unsigned int* Vd = pp.htp + (size_t)(rg+1)*3*PLN + (size_t)b*S*64 + lane;
        float accD[6] = {0,0,0,0,0,0};
        #pragma unroll 2
        for (int j = rlo[rg] + wave; j < rhi[rg]; j += 4){
            f32x4 ma = wMa[j], mb = wMb[j];
            f32x4 da = wDa[j], db = wDb[j];
            size_t toff = (size_t)f2i(mb[2])*64;
            unsigned int u0 = Vm[toff];
            unsigned int u1 = Vm[toff + PLN];
            unsigned int u2 = Vm[toff + 2*PLN];
            accM[0] += ma[0]*blo(u0); accM[1] += ma[1]*bhi(u0);
            accM[2] += ma[2]*blo(u1); accM[3] += ma[3]*bhi(u1);
            accM[4] += mb[0]*blo(u2); accM[5] += mb[1]*bhi(u2);
            if (db[2] == 0.f){
                unsigned int d0 = Vd[toff];
                unsigned int d1 = Vd[toff + PLN];
                unsigned int d2 = Vd[toff + 2*PLN];
                accD[0] += da[0]*blo(d0); accD[1] += da[1]*bhi(d0);
                accD[2] += da[2]*blo(d1); accD[3] += da[3]*bhi(d1);
                accD[4] += db[0]*blo(d2); accD[5] += db[1]*bhi(d2);
            }
        }
        // flush deputy rg+1
        {
            f32x4 pa = {accD[0], accD[1], accD[2], accD[3]};
            f32x4 pb = {accD[4], accD[5], 0.f, 0.f};
            paccA[wave][lane] = pa; paccB[wave][lane] = pb;
        }
        __syncthreads();
        if (wave == 0){
            unsigned short* outp = pp.h1c4 + ((size_t)(rg+1)*ROWS + row)*HHD;
            bool has = rhi[rg] > rlo[rg];
            const float* mv = pp.meanV1p + ((size_t)(rg+1)*B + b)*512 + lane*8;
            f32x4 q0 = paccA[0][lane], q1 = paccA[1][lane], q2 = paccA[2][lane], q3 = paccA[3][lane];
            f32x4 r0 = paccB[0][lane], r1 = paccB[1][lane], r2 = paccB[2][lane], r3 = paccB[3][lane];
            float sum6[6];
            sum6[0] = q0[0]+q1[0]+q2[0]+q3[0];
            sum6[1] = q0[1]+q1[1]+q2[1]+q3[1];
            sum6[2] = q0[2]+q1[2]+q2[2]+q3[2];
            sum6[3] = q0[3]+q1[3]+q2[3]+q3[3];
            sum6[4] = r0[0]+r1[0]+r2[0]+r3[0];
            sum6[5] = r0[1]+r1[1]+r2[1]+r3[1];
            #pragma unroll
            for (int h = 0; h < 6; h++){
                float den = pdenD[0][rg][h] + pdenD[1][rg][h];
                float v = has ? sum6[h]/den : mv[h];
                v = v > 0.f ? v : __expf(v) - 1.f;   // ELU
                outp[h*64 + lane] = f2bf(v);
            }
        }
        __syncthreads();
    }
    // flush main (c.x >= 1 always: self-loop)
    {
        f32x4 pa = {accM[0], accM[1], accM[2], accM[3]};
        f32x4 pb = {accM[4], accM[5], 0.f, 0.f};
        paccA[wave][lane] = pa; paccB[wave][lane] = pb;
    }
    __syncthreads();
    if (wave == 0){
        unsigned short* outp = pp.h1c4 + (size_t)row*HHD;
        f32x4 q0 = paccA[0][lane], q1 = paccA[1][lane], q2 = paccA[2][lane], q3 = paccA[3][lane];
        f32x4 r0 = paccB[0][lane], r1 = paccB[1][lane], r2 = paccB[2][lane], r3 = paccB[3][lane];
        float sum6[6];
        sum6[0] = q0[0]+q1[0]+q2[0]+q3[0];
        sum6[1] = q0[1]+q1[1]+q2[1]+q3[1];
        sum6[2] = q0[2]+q1[2]+q2[2]+q3[2];
        sum6[3] = q0[3]+q1[3]+q2[3]+q3[3];
        sum6[4] = r0[0]+r1[0]+r2[0]+r3[0];
        sum6[5] = r0[1]+r1[1]+r2[1]+r3[1];
        #pragma unroll
        for (int h = 0; h < 6; h++){
            float den = pdenM[0][h] + pdenM[1][h];
            float v = sum6[h]/den;
            v = v > 0.f ? v : __expf(v) - 1.f;   // ELU
            outp[h*64 + lane] = f2bf(v);
        }
    }
}

// ---------- GEMM2 (h1@W2) + fused f2s/f2d + colmean ----------
// grid (D/128=2, ROWS/64, 4)
__global__ __launch_bounds__(256, 4) void gemm2_kernel(P pp)
{
    __shared__ float ep[2][2][64][17];
    int tid = threadIdx.x, wave = tid >> 6, lane = tid & 63;
    int quad = lane >> 4, l16 = lane & 15;
    int e = blockIdx.z;
    int m0 = blockIdx.x*128;
    int n0 = blockIdx.y*64;
    f32x4 z4 = {0.f,0.f,0.f,0.f};
    const unsigned short* arow0 = pp.w2nk + (size_t)e*D*HHD + (size_t)(m0 + wave*16 + l16)*HHD + quad*8;
    const unsigned short* arow1 = arow0 + (size_t)64*HHD;
    const unsigned short* brow[4];
    #pragma unroll
    for (int j = 0; j < 4; j++)
        brow[j] = pp.h1c4 + (size_t)e*ROWS*HHD + (size_t)(n0 + j*16 + l16)*HHD + quad*8;
    f32x4 acc[8] = {z4, z4, z4, z4, z4, z4, z4, z4};
    bf8_t a0F = *(const bf8_t*)(arow0);
    bf8_t a1F = *(const bf8_t*)(arow1);
    bf8_t bF[4];
    #pragma unroll
    for (int j = 0; j < 4; j++) bF[j] = *(const bf8_t*)(brow[j]);
    #pragma unroll
    for (int it = 0; it < HHD/32; it++){
        bf8_t a0C = a0F, a1C = a1F;
        bf8_t bC[4] = {bF[0], bF[1], bF[2], bF[3]};
        if (it + 1 < HHD/32){
            int kn = (it + 1)*32;
            a0F = *(const bf8_t*)(arow0 + kn);
            a1F = *(const bf8_t*)(arow1 + kn);
            #pragma unroll
            for (int j = 0; j < 4; j++) bF[j] = *(const bf8_t*)(brow[j] + kn);
        }
        #pragma unroll
        for (int j = 0; j < 4; j++){
            acc[j]   = __builtin_amdgcn_mfma_f32_16x16x32_bf16(a0C, bC[j], acc[j],   0, 0, 0);
            acc[4+j] = __builtin_amdgcn_mfma_f32_16x16x32_bf16(a1C, bC[j], acc[4+j], 0, 0, 0);
        }
    }
    int b = n0 >> 10;
    int mbase0 = m0 + wave*16 + quad*4;
    int mbase1 = mbase0 + 64;
    #pragma unroll
    for (int j = 0; j < 4; j++){
        int row = n0 + j*16 + l16;
        ushort4 o0, o1;
        o0.x = f2bf(acc[j][0]);   o0.y = f2bf(acc[j][1]);
        o0.z = f2bf(acc[j][2]);   o0.w = f2bf(acc[j][3]);
        o1.x = f2bf(acc[4+j][0]); o1.y = f2bf(acc[4+j][1]);
        o1.z = f2bf(acc[4+j][2]); o1.w = f2bf(acc[4+j][3]);
        *(ushort4*)(pp.h2n4 + ((size_t)e*ROWS + row)*D + mbase0) = o0;
        *(ushort4*)(pp.h2n4 + ((size_t)e*ROWS + row)*D + mbase1) = o1;
    }
    const float* a2sp = (e == 0) ? pp.main_a2s : pp.dep_a2s + (size_t)(e-1)*D;
    const float* a2dp = (e == 0) ? pp.main_a2d : pp.dep_a2d + (size_t)(e-1)*D;
    float s0v[4], d0v[4], s1v[4], d1v[4];
    #pragma unroll
    for (int r = 0; r < 4; r++){
        s0v[r] = a2sp[mbase0 + r]; d0v[r] = a2dp[mbase0 + r];
        s1v[r] = a2sp[mbase1 + r]; d1v[r] = a2dp[mbase1 + r];
    }
    #pragma unroll
    for (int j = 0; j < 4; j++){
        float ps0 = 0.f, pd0 = 0.f, ps1 = 0.f, pd1 = 0.f;
        #pragma unroll
        for (int r = 0; r < 4; r++){
            ps0 += acc[j][r]*s0v[r];   pd0 += acc[j][r]*d0v[r];
            ps1 += acc[4+j][r]*s1v[r]; pd1 += acc[4+j][r]*d1v[r];
        }
        ep[0][0][j*16 + l16][wave*4 + quad] = ps0;
        ep[0][1][j*16 + l16][wave*4 + quad] = pd0;
        ep[1][0][j*16 + l16][wave*4 + quad] = ps1;
        ep[1][1][j*16 + l16][wave*4 + quad] = pd1;
    }
    #pragma unroll
    for (int r = 0; r < 4; r++){
        float cm0 = acc[0][r] + acc[1][r] + acc[2][r] + acc[3][r];
        float cm1 = acc[4][r] + acc[5][r] + acc[6][r] + acc[7][r];
        for (int off = 8; off; off >>= 1){
            cm0 += __shfl_down(cm0, off, 16);
            cm1 += __shfl_down(cm1, off, 16);
        }
        if (l16 == 0){
            atomicAdd(pp.meanV2 + ((size_t)e*B + b)*D + mbase0 + r, cm0*(1.f/(float)S));
            atomicAdd(pp.meanV2 + ((size_t)e*B + b)*D + mbase1 + r, cm1*(1.f/(float)S));
        }
    }
    __syncthreads();
    {
        int hh = tid >> 7, arr = (tid >> 6) & 1, sl = tid & 63;
        float sum = 0.f;
        #pragma unroll
        for (int i = 0; i < 16; i++) sum += ep[hh][arr][sl][i];
        int n = n0 + sl;
        float* dst = arr ? pp.f2d4 : pp.f2s4;
        atomicAdd(dst + (size_t)e*ROWS + n, sum);
    }
}

// ---------- attn2 + blend: waves 0,1 main; waves 2,3 active deputies ----------
// grid (S, B), 256 threads
__global__ __launch_bounds__(256) void a2_kernel(P pp)
{
    __shared__ float2 wrec0[MAXN];
    __shared__ float2 wrec1[MAXN];
    __shared__ float pacc[3][256];
    __shared__ float pden[4][4];
    int tid = threadIdx.x;
    int wave = tid >> 6, lane = tid & 63;
    int s = blockIdx.x, b = blockIdx.y;
    int row = b*S + s;
    int4 c = pp.nbc[row];
    float rm0 = pp.rmask[row], rm1 = pp.rmask[ROWS + row], rm2 = pp.rmask[2*ROWS + row];
    const short* nl = pp.nbr + (size_t)row*MAXN;
    // ---- weight phase ----
    if (wave < 2){
        int i = wave*64 + lane;
        float w = 0.f;
        if (i < c.x){
            int t = nl[i];
            float fs = pp.f2s4[row];
            w = __expf(leaky(fs + pp.f2d4[(size_t)b*S + t]));
            float2 r; r.x = w; r.y = i2f(t);
            wrec0[i] = r;
        }
        float dsum = w;
        for (int o2 = 32; o2; o2 >>= 1) dsum += __shfl_down(dsum, o2);
        if (lane == 0) pden[wave][0] = dsum;
    } else {
        int i = (wave - 2)*64 + lane;
        float w = 0.f, d1 = 0.f, d2 = 0.f, d3 = 0.f;
        if (i < c.x){
            int t = nl[i];
            int tag = (i < c.y) ? 1 : ((i < c.z) ? 2 : 3);
            float act = (tag == 1) ? rm0 : ((tag == 2) ? rm1 : rm2);
            if (act != 0.f){
                float fs = pp.f2s4[(size_t)tag*ROWS + row];
                w = __expf(leaky(fs + pp.f2d4[(size_t)tag*ROWS + (size_t)b*S + t]));
            }
            float2 r; r.x = w; r.y = i2f(t);
            wrec1[i] = r;
            if (tag == 1) d1 = w; else if (tag == 2) d2 = w; else d3 = w;
        }
        for (int o2 = 32; o2; o2 >>= 1){
            d1 += __shfl_down(d1, o2);
            d2 += __shfl_down(d2, o2);
            d3 += __shfl_down(d3, o2);
        }
        if (lane == 0){ pden[wave][1] = d1; pden[wave][2] = d2; pden[wave][3] = d3; }
    }
    __syncthreads();
    // ---- gather phase ----
    float acc[4] = {0.f, 0.f, 0.f, 0.f};
    if (wave < 2){
        float inv = 1.f/(pden[0][0] + pden[1][0]);   // c.x >= 1 (self-loop) always
        const unsigned short* V = pp.h2n4 + (size_t)b*S*D;
        #pragma unroll 4
        for (int j = wave; j < c.x; j += 2){
            float2 r = wrec0[j];
            float wv = r.x*inv;
            int t = f2i(r.y);
            const unsigned short* vp = V + (size_t)t*D + lane*4;
            uint2 dv = *(const uint2*)vp;
            acc[0] += wv*blo(dv.x); acc[1] += wv*bhi(dv.x);
            acc[2] += wv*blo(dv.y); acc[3] += wv*bhi(dv.y);
        }
    } else {
        int rlo[3] = {0, c.y, c.z};
        int rhi[3] = {c.y, c.z, c.x};
        float ract[3] = {rm0, rm1, rm2};
        for (int rg = 0; rg < 3; rg++){
            if (ract[rg] == 0.f || rhi[rg] <= rlo[rg]) continue;
            float inv = 1.f/(pden[2][rg+1] + pden[3][rg+1]);
            const unsigned short* V = pp.h2n4 + ((size_t)(rg+1)*ROWS + (size_t)b*S)*D;
            #pragma unroll 4
            for (int j = rlo[rg] + (wave - 2); j < rhi[rg]; j += 2){
                float2 r = wrec1[j];
                float wv = r.x*inv;
                int t = f2i(r.y);
                const unsigned short* vp = V + (size_t)t*D + lane*4;
                uint2 dv = *(const uint2*)vp;
                acc[0] += wv*blo(dv.x); acc[1] += wv*bhi(dv.x);
                acc[2] += wv*blo(dv.y); acc[3] += wv*bhi(dv.y);
            }
        }
    }
    if (wave >= 1){
        #pragma unroll
        for (int q = 0; q < 4; q++) pacc[wave-1][lane*4 + q] = acc[q];
    }
    __syncthreads();
    // ---- combine + blend (wave 0) ----
    if (wave == 0){
        float4 g4 = *(const float4*)(pp.gatebuf + (size_t)row*D + lane*4);
        float dep_mv[4] = {0.f, 0.f, 0.f, 0.f};
        if (rm0 != 0.f && c.y == 0){
            float4 mv = *(const float4*)(pp.meanV2 + ((size_t)1*B + b)*D + lane*4);
            dep_mv[0] += mv.x; dep_mv[1] += mv.y; dep_mv[2] += mv.z; dep_mv[3] += mv.w;
        }
        if (rm1 != 0.f && c.z == c.y){
            float4 mv = *(const float4*)(pp.meanV2 + ((size_t)2*B + b)*D + lane*4);
            dep_mv[0] += mv.x; dep_mv[1] += mv.y; dep_mv[2] += mv.z; dep_mv[3] += mv.w;
        }
        if (rm2 != 0.f && c.x == c.z){
            float4 mv = *(const float4*)(pp.meanV2 + ((size_t)3*B + b)*D + lane*4);
            dep_mv[0] += mv.x; dep_mv[1] += mv.y; dep_mv[2] += mv.z; dep_mv[3] += mv.w;
        }
        float g[4] = {g4.x, g4.y, g4.z, g4.w};
        float4 o;
        float* op = &o.x;
        #pragma unroll
        for (int q = 0; q < 4; q++){
            int col = lane*4 + q;
            float a0 = acc[q] + pacc[0][col];
            float dep = pacc[1][col] + pacc[2][col] + dep_mv[q];
            op[q] = g[q]*a0 + (1.f - g[q])*dep;
        }
        *(float4*)(pp.outp + (size_t)row*D + lane*4) = o;
    }
    if (blockIdx.x == 0 && blockIdx.y == 0 && tid == 0){
        float mc = pp.sumBuf[0] / (float)(ROWS*D);
        pp.outp[ROWS*D]     = fabsf(mc - 0.6f)*0.01f;
        pp.outp[ROWS*D + 1] = mc;
    }
}

extern "C" void kernel_launch(void* const* d_in, const int* in_sizes, int n_in,
                              void* d_out, int out_size, void* d_ws, size_t ws_size,
                              hipStream_t stream)
{
    P hp;
    hp.feature  = (const float*)d_in[0];
    hp.adj      = (const float*)d_in[1];
    hp.main_W1  = (const float*)d_in[2];
    hp.main_a1s = (const float*)d_in[3];
    hp.main_a1d = (const float*)d_in[4];
    hp.main_W2  = (const float*)d_in[5];
    hp.main_a2s = (const float*)d_in[6];
    hp.main_a2d = (const float*)d_in[7];
    hp.dep_W1   = (const float*)d_in[8];
    hp.dep_a1s  = (const float*)d_in[9];
    hp.dep_a1d  = (const float*)d_in[10];
    hp.dep_W2   = (const float*)d_in[11];
    hp.dep_a2s  = (const float*)d_in[12];
    hp.dep_a2d  = (const float*)d_in[13];
    hp.router_W = (const float*)d_in[14];
    hp.blend_W  = (const float*)d_in[15];
    hp.blend_b  = (const float*)d_in[16];
    hp.doc_p    = (const int*)d_in[17];
    hp.sect_p   = (const int*)d_in[18];

    char* ws = (char*)d_ws;
    size_t off = 0;
    hp.featbf = (unsigned short*)(ws + off); off += (size_t)ROWS*D*2;        // 2 MB
    hp.nbr    = (short*)(ws + off);          off += (size_t)ROWS*MAXN*2;     // 1 MB
    hp.nbc    = (int4*)(ws + off);           off += (size_t)ROWS*16;         // 64 KB
    hp.w1nk   = (unsigned short*)(ws + off); off += (size_t)4*HHD*D*2;
    hp.w2nk   = (unsigned short*)(ws + off); off += (size_t)4*D*HHD*2;
    hp.bwt    = (unsigned short*)(ws + off); off += (size_t)D*D*2;
    hp.es8 = (float*)(ws + off); off += (size_t)4*B*S*8*4;   // 512 KB
    hp.ed8 = (float*)(ws + off); off += (size_t)4*B*S*8*4;   // 512 KB
    hp.gatebuf = (float*)(ws + off); off += (size_t)ROWS*D*4;                // 4 MB
    hp.htp  = (unsigned int*)(ws + off);     off += (size_t)12*PLN*4;        // 12 MB compact planes
    hp.h2n4 = (unsigned short*)(ws + off); off += (size_t)4*ROWS*D*2;        // 8 MB
    hp.h1c4 = (unsigned short*)(ws + off); off += (size_t)4*ROWS*HHD*2;      // 12 MB
    // contiguous zero region (NZERO floats) starts at f2s4:
    hp.f2s4    = (float*)(ws + off); off += (size_t)4*ROWS*4;
    hp.f2d4    = (float*)(ws + off); off += (size_t)4*ROWS*4;
    hp.meanV1p = (float*)(ws + off); off += (size_t)4*B*512*4;
    hp.meanV2  = (float*)(ws + off); off += (size_t)4*B*D*4;
    hp.sumBuf  = (float*)(ws + off); off += 128;
    hp.rmask   = (float*)(ws + off); off += (size_t)NE*ROWS*4;
    hp.outp    = (float*)d_out;

    prep_kernel<<<PB_TOTAL, 256, 0, stream>>>(hp);
    gemm1_kernel<<<dim3(3, ROWS/64, 5), 256, 0, stream>>>(hp);
    a1_kernel<<<dim3(S, B), 256, 0, stream>>>(hp);
    gemm2_kernel<<<dim3(D/128, ROWS/64, 4), 256, 0, stream>>>(hp);
    a2_kernel<<<dim3(S, B), 256, 0, stream>>>(hp);
}